// Round 4
// baseline (1109.923 us; speedup 1.0000x reference)
//
#include <hip/hip_runtime.h>

#define B_TOT 65536
#define T_LEN 34
#define HD 64
#define LOG2E 1.44269504088896340736f

typedef __attribute__((ext_vector_type(8))) short short8b;
typedef __attribute__((ext_vector_type(4))) short short4b;
typedef __attribute__((ext_vector_type(4))) float f32x4;

__device__ __forceinline__ float frcp(float x){ return __builtin_amdgcn_rcpf(x); }
__device__ __forceinline__ float fexp2(float x){ return __builtin_amdgcn_exp2f(x); }
__device__ __forceinline__ float fsigmoid(float x){ return frcp(1.0f+__expf(-x)); }
__device__ __forceinline__ float felu(float x){ return x>0.0f ? x : (__expf(x)-1.0f); }

__device__ __forceinline__ unsigned short f2bf_rne(float f){
    unsigned int u = __float_as_uint(f);
    u += 0x7FFFu + ((u >> 16) & 1u);
    return (unsigned short)(u >> 16);
}
__device__ __forceinline__ float bf2f(unsigned short h){
    return __uint_as_float(((unsigned int)h) << 16);
}
__device__ __forceinline__ unsigned short f2bf_fast(float f){
    unsigned int u = __float_as_uint(f);
    return (unsigned short)((u + 0x8000u) >> 16);
}
__device__ __forceinline__ void split8(const float4& a, const float4& b,
                                       short8b& hi, short8b& lo){
    float f[8] = {a.x,a.y,a.z,a.w,b.x,b.y,b.z,b.w};
    #pragma unroll
    for (int i = 0; i < 8; ++i){
        unsigned short h = f2bf_rne(f[i]);
        hi[i] = (short)h;
        lo[i] = (short)f2bf_rne(f[i] - bf2f(h));
    }
}

// ---------------- Kernel A: forward-fill + GRU (MFMA) + attention pooling ----------------
// 4 waves/block, 16 rows/wave. 13 B-tiles: 12 gate tiles (Whh pre-scaled by
// -log2e for r,z and +2log2e for n; bias folded into MFMA C-init) + 1 score
// tile (cols 0,1 = log2e*swT, log2e*swM). Gates use raw v_exp/v_rcp.
__global__ __launch_bounds__(256, 3)
void gru_attn_mfma(const float* __restrict__ Xin, const float* __restrict__ FA,
                   const float* __restrict__ Wih, const float* __restrict__ Whh,
                   const float* __restrict__ bih, const float* __restrict__ bhh,
                   const float* __restrict__ swT, const float* __restrict__ swM,
                   float* __restrict__ hT_out, float* __restrict__ hM_out)
{
    __shared__ __align__(16) unsigned short WF[26*512];   // 26 KB
    __shared__ __align__(16) unsigned short HL[4][1024];  // 8 KB
    __shared__ __align__(8)  float XF[4][16][T_LEN][2];   // 17 KB

    const int tid  = threadIdx.x;
    const int lane = tid & 63;
    const int wv   = tid >> 6;
    const int l16  = lane & 15;
    const int lhi  = lane >> 4;

    // ---- stage B-fragments (frag f: ks=f/13, nt=f%13) ----
    for (int f = wv; f < 26; f += 4) {
        int ks = f / 13, nt = f % 13;
        int k0 = ks*32 + lhi*8;
        unsigned short* dst = &WF[f*512 + lane*8];
        if (nt < 12) {
            int u  = nt*16 + l16;
            float scale = (nt < 8) ? -LOG2E : 2.0f*LOG2E;
            const float4 w0 = *reinterpret_cast<const float4*>(&Whh[u*64 + k0]);
            const float4 w1 = *reinterpret_cast<const float4*>(&Whh[u*64 + k0 + 4]);
            dst[0]=f2bf_rne(w0.x*scale); dst[1]=f2bf_rne(w0.y*scale);
            dst[2]=f2bf_rne(w0.z*scale); dst[3]=f2bf_rne(w0.w*scale);
            dst[4]=f2bf_rne(w1.x*scale); dst[5]=f2bf_rne(w1.y*scale);
            dst[6]=f2bf_rne(w1.z*scale); dst[7]=f2bf_rne(w1.w*scale);
        } else {
            const float* src = (l16 == 1) ? swM : swT;
            #pragma unroll
            for (int j = 0; j < 8; ++j)
                dst[j] = (l16 < 2) ? f2bf_rne(src[k0+j]*LOG2E) : (unsigned short)0;
        }
    }

    #pragma unroll
    for (int i = 0; i < 16; ++i) HL[wv][i*64 + lane] = 0;

    const int rowbase = blockIdx.x*64 + wv*16;

    // ---- forward fill (segmented LOCF) via lane prefix-max ----
    for (int rr = 0; rr < 16; ++rr) {
        int row = rowbase + rr;
        float X = 0.0f, fa = 0.0f; int idx = -1;
        if (lane < T_LEN) {
            X  = Xin[row*T_LEN + lane];
            fa = FA [row*T_LEN + lane];
            if (X != 0.0f) idx = lane;
        }
        #pragma unroll
        for (int off = 1; off < 64; off <<= 1) {
            int v = __shfl_up(idx, off);
            if (lane >= off && v > idx) idx = v;
        }
        int gsrc = idx < 0 ? 0 : idx;
        float Xg = __shfl(X,  gsrc);
        float fg = __shfl(fa, gsrc);
        if (idx < 0) { Xg = 0.0f; fg = 0.0f; }
        if (lane < T_LEN) { XF[wv][rr][lane][0] = Xg; XF[wv][rr][lane][1] = fg; }
    }

    // ---- per-lane constants (pre-scaled for exp2) ----
    float wrx[4], wrf[4], wzx[4], wzf[4], wnx[4], wnf[4], bihn[4], biasD[12];
    #pragma unroll
    for (int nt = 0; nt < 4; ++nt) {
        int ul = nt*16 + l16;
        wrx[nt] = -LOG2E*Wih[ ul*2     ]; wrf[nt] = -LOG2E*Wih[ ul*2     +1];
        wzx[nt] = -LOG2E*Wih[(64+ul)*2 ]; wzf[nt] = -LOG2E*Wih[(64+ul)*2 +1];
        wnx[nt] = 2.0f*LOG2E*Wih[(128+ul)*2]; wnf[nt] = 2.0f*LOG2E*Wih[(128+ul)*2+1];
        bihn[nt] = 2.0f*LOG2E*bih[128+ul];
    }
    #pragma unroll
    for (int nt = 0; nt < 12; ++nt) {
        int u = nt*16 + l16;
        biasD[nt] = (nt < 8) ? -LOG2E*(bih[u] + bhh[u]) : 2.0f*LOG2E*bhh[u];
    }

    __syncthreads();

    const int swz   = (l16 & 7) << 3;
    const int aoff0 = l16*64 + ((     lhi*8) ^ swz);
    const int aoff1 = l16*64 + ((32 + lhi*8) ^ swz);
    const int bcast = lane & 48;

    float hreg[4][4] = {};
    float numT[4][4] = {}, numM[4][4] = {};
    float denT[4]    = {}, denM[4]    = {};

    const unsigned short* HLr = HL[wv];
    unsigned short*       HLw = HL[wv];

    for (int t = 0; t < T_LEN; ++t) {
        short8b a0 = *reinterpret_cast<const short8b*>(&HLr[aoff0]);
        short8b a1 = *reinterpret_cast<const short8b*>(&HLr[aoff1]);
        // score tile first so pooling overlaps the gate MFMAs
        f32x4 accS = (f32x4){0.f,0.f,0.f,0.f};
        accS = __builtin_amdgcn_mfma_f32_16x16x32_bf16(
            a0, *reinterpret_cast<const short8b*>(&WF[12*512 + lane*8]), accS, 0,0,0);
        accS = __builtin_amdgcn_mfma_f32_16x16x32_bf16(
            a1, *reinterpret_cast<const short8b*>(&WF[25*512 + lane*8]), accS, 0,0,0);
        f32x4 acc[12];
        #pragma unroll
        for (int nt = 0; nt < 12; ++nt) {
            float b = biasD[nt];
            acc[nt] = (f32x4){b, b, b, b};
            acc[nt] = __builtin_amdgcn_mfma_f32_16x16x32_bf16(
                a0, *reinterpret_cast<const short8b*>(&WF[ nt     *512 + lane*8]), acc[nt], 0,0,0);
            acc[nt] = __builtin_amdgcn_mfma_f32_16x16x32_bf16(
                a1, *reinterpret_cast<const short8b*>(&WF[(13+nt)*512 + lane*8]), acc[nt], 0,0,0);
        }
        // pooling of h_t (the state entering this step) — skip t=0 (h=0 not an output)
        if (t) {
            #pragma unroll
            for (int q = 0; q < 4; ++q) {
                float e  = fexp2(accS[q]);
                float eT = __shfl(e, bcast);
                float eM = __shfl(e, bcast | 1);
                denT[q] += eT; denM[q] += eM;
                #pragma unroll
                for (int nt = 0; nt < 4; ++nt) {
                    numT[q][nt] = fmaf(eT, hreg[q][nt], numT[q][nt]);
                    numM[q][nt] = fmaf(eM, hreg[q][nt], numM[q][nt]);
                }
            }
        }
        // gates (pre-scaled: r,z use exp2(-L*x); n uses exp2(2L*v))
        #pragma unroll
        for (int q = 0; q < 4; ++q) {
            const int rloc = lhi*4 + q;
            const int rs   = (rloc & 7) << 3;
            float2 xf = *reinterpret_cast<const float2*>(&XF[wv][rloc][t][0]);
            float x = xf.x, fv = xf.y;
            #pragma unroll
            for (int nt = 0; nt < 4; ++nt) {
                float Sr = acc[nt][q], Sz = acc[nt+4][q], Sn = acc[nt+8][q];
                float ur = fmaf(wrx[nt], x, fmaf(wrf[nt], fv, Sr));
                float r  = frcp(1.0f + fexp2(ur));
                float uz = fmaf(wzx[nt], x, fmaf(wzf[nt], fv, Sz));
                float z  = frcp(1.0f + fexp2(uz));
                float xn = fmaf(wnx[nt], x, fmaf(wnf[nt], fv, bihn[nt]));
                float v  = fmaf(r, Sn, xn);
                float n  = fmaf(-2.0f, frcp(1.0f + fexp2(v)), 1.0f);
                float hn = fmaf(z, hreg[q][nt] - n, n);
                hreg[q][nt] = hn;
                HLw[rloc*64 + ((((nt<<4) + l16)) ^ rs)] = f2bf_fast(hn);
            }
        }
    }

    // ---- pool the final state h_T ----
    {
        short8b a0 = *reinterpret_cast<const short8b*>(&HLr[aoff0]);
        short8b a1 = *reinterpret_cast<const short8b*>(&HLr[aoff1]);
        f32x4 accS = (f32x4){0.f,0.f,0.f,0.f};
        accS = __builtin_amdgcn_mfma_f32_16x16x32_bf16(
            a0, *reinterpret_cast<const short8b*>(&WF[12*512 + lane*8]), accS, 0,0,0);
        accS = __builtin_amdgcn_mfma_f32_16x16x32_bf16(
            a1, *reinterpret_cast<const short8b*>(&WF[25*512 + lane*8]), accS, 0,0,0);
        #pragma unroll
        for (int q = 0; q < 4; ++q) {
            float e  = fexp2(accS[q]);
            float eT = __shfl(e, bcast);
            float eM = __shfl(e, bcast | 1);
            denT[q] += eT; denM[q] += eM;
            #pragma unroll
            for (int nt = 0; nt < 4; ++nt) {
                numT[q][nt] = fmaf(eT, hreg[q][nt], numT[q][nt]);
                numM[q][nt] = fmaf(eM, hreg[q][nt], numM[q][nt]);
            }
        }
    }

    #pragma unroll
    for (int q = 0; q < 4; ++q) {
        int row = rowbase + lhi*4 + q;
        float rT = frcp(denT[q]), rM = frcp(denM[q]);
        #pragma unroll
        for (int nt = 0; nt < 4; ++nt) {
            hT_out[row*HD + nt*16 + l16] = numT[q][nt]*rT;
            hM_out[row*HD + nt*16 + l16] = numM[q][nt]*rM;
        }
    }
}

// ---------------- Kernel B: MFMA MLP heads + T10/M0 + X_out ----------------
__global__ __launch_bounds__(256)
void mlp_mfma(const float* __restrict__ hT, const float* __restrict__ hM,
    const float* __restrict__ TW1, const float* __restrict__ Tb1,
    const float* __restrict__ TW2, const float* __restrict__ Tb2,
    const float* __restrict__ TW3, const float* __restrict__ Tb3,
    const float* __restrict__ MW1, const float* __restrict__ Mb1,
    const float* __restrict__ MW2, const float* __restrict__ Mb2,
    const float* __restrict__ MW3, const float* __restrict__ Mb3,
    const float* __restrict__ FA, const float* __restrict__ TR,
    float* __restrict__ out)
{
    __shared__ __align__(16) unsigned short xh[2*64*64];
    __shared__ __align__(16) unsigned short h1s[64*256];
    __shared__ float praw[4][64];
    __shared__ float rawv[2][64];
    __shared__ float Es[64], M0s[64];

    const int tid  = threadIdx.x;
    const int lane = tid & 63;
    const int wv   = tid >> 6;
    const int l16  = lane & 15;
    const int lhi  = lane >> 4;
    const int row0 = blockIdx.x*64;

    {
        int r  = tid >> 2;
        int k0 = (tid & 3) * 16;
        int rx = r & 7;
        const float* pT = &hT[(row0+r)*64 + k0];
        const float* pM = &hM[(row0+r)*64 + k0];
        #pragma unroll
        for (int j = 0; j < 4; ++j) {
            float4 vT = *reinterpret_cast<const float4*>(pT + 4*j);
            float4 vM = *reinterpret_cast<const float4*>(pM + 4*j);
            int kk = k0 + 4*j;
            int ad = r*64 + ((((kk>>3) ^ rx))<<3) + (kk&7);
            short4b sT = { (short)f2bf_rne(vT.x), (short)f2bf_rne(vT.y),
                           (short)f2bf_rne(vT.z), (short)f2bf_rne(vT.w) };
            short4b sM = { (short)f2bf_rne(vM.x), (short)f2bf_rne(vM.y),
                           (short)f2bf_rne(vM.z), (short)f2bf_rne(vM.w) };
            *reinterpret_cast<short4b*>(&xh[ad])        = sT;
            *reinterpret_cast<short4b*>(&xh[4096 + ad]) = sM;
        }
        for (int i = tid; i < 64*24; i += 256) {
            int rr = i / 24, kk = 200 + i % 24;
            h1s[rr*256 + ((((kk>>3) ^ (rr&7)))<<3) + (kk&7)] = 0;
        }
    }
    __syncthreads();

    for (int brn = 0; brn < 2; ++brn) {
        const float* W1 = brn ? MW1 : TW1; const float* b1 = brn ? Mb1 : Tb1;
        const float* W2 = brn ? MW2 : TW2; const float* b2 = brn ? Mb2 : Tb2;
        const float* W3 = brn ? MW3 : TW3; const float* b3 = brn ? Mb3 : Tb3;

        for (int s = 0; s < 4; ++s) {
            int nt = wv + 4*s;
            if (nt > 12) break;
            int n  = nt*16 + l16;
            int nc = n < 200 ? n : 199;
            float bv = b1[nc];
            f32x4 acc[4];
            #pragma unroll
            for (int mt = 0; mt < 4; ++mt) acc[mt] = (f32x4){bv,bv,bv,bv};
            #pragma unroll
            for (int ks = 0; ks < 2; ++ks) {
                int k0 = ks*32 + lhi*8;
                const float* wp = &W1[nc*64 + k0];
                float4 w0 = *reinterpret_cast<const float4*>(wp);
                float4 w1 = *reinterpret_cast<const float4*>(wp + 4);
                short8b bh, bl;
                split8(w0, w1, bh, bl);
                #pragma unroll
                for (int mt = 0; mt < 4; ++mt) {
                    int rr = mt*16 + l16;
                    short8b a = *reinterpret_cast<const short8b*>(
                        &xh[brn*4096 + rr*64 + ((((k0>>3) ^ (rr&7)))<<3)]);
                    acc[mt] = __builtin_amdgcn_mfma_f32_16x16x32_bf16(a, bh, acc[mt], 0,0,0);
                    acc[mt] = __builtin_amdgcn_mfma_f32_16x16x32_bf16(a, bl, acc[mt], 0,0,0);
                }
            }
            if (n < 200) {
                #pragma unroll
                for (int mt = 0; mt < 4; ++mt) {
                    #pragma unroll
                    for (int q = 0; q < 4; ++q) {
                        int rr = mt*16 + lhi*4 + q;
                        h1s[rr*256 + ((((n>>3) ^ (rr&7)))<<3) + (n&7)] =
                            f2bf_rne(felu(acc[mt][q]));
                    }
                }
            }
        }
        __syncthreads();

        float p[4][4] = {};
        for (int s = 0; s < 4; ++s) {
            int nt = wv + 4*s;
            if (nt > 12) break;
            int n  = nt*16 + l16;
            int nc = n < 200 ? n : 199;
            float w3v = (n < 200) ? W3[nc] : 0.0f;
            float bv = b2[nc];
            f32x4 acc[4];
            #pragma unroll
            for (int mt = 0; mt < 4; ++mt) acc[mt] = (f32x4){bv,bv,bv,bv};
            for (int ks = 0; ks < 7; ++ks) {
                int k0 = ks*32 + lhi*8;
                short8b bh, bl;
                if (k0 + 8 <= 200) {
                    const float* wp = &W2[nc*200 + k0];
                    float4 w0 = *reinterpret_cast<const float4*>(wp);
                    float4 w1 = *reinterpret_cast<const float4*>(wp + 4);
                    split8(w0, w1, bh, bl);
                } else {
                    #pragma unroll
                    for (int i = 0; i < 8; ++i) { bh[i] = 0; bl[i] = 0; }
                }
                #pragma unroll
                for (int mt = 0; mt < 4; ++mt) {
                    int rr = mt*16 + l16;
                    short8b a = *reinterpret_cast<const short8b*>(
                        &h1s[rr*256 + ((((k0>>3) ^ (rr&7)))<<3)]);
                    acc[mt] = __builtin_amdgcn_mfma_f32_16x16x32_bf16(a, bh, acc[mt], 0,0,0);
                    acc[mt] = __builtin_amdgcn_mfma_f32_16x16x32_bf16(a, bl, acc[mt], 0,0,0);
                }
            }
            #pragma unroll
            for (int mt = 0; mt < 4; ++mt)
                #pragma unroll
                for (int q = 0; q < 4; ++q)
                    p[mt][q] = fmaf(w3v, felu(acc[mt][q]), p[mt][q]);
        }
        #pragma unroll
        for (int off = 1; off < 16; off <<= 1) {
            #pragma unroll
            for (int mt = 0; mt < 4; ++mt)
                #pragma unroll
                for (int q = 0; q < 4; ++q)
                    p[mt][q] += __shfl_xor(p[mt][q], off);
        }
        if (l16 == 0) {
            #pragma unroll
            for (int mt = 0; mt < 4; ++mt)
                #pragma unroll
                for (int q = 0; q < 4; ++q)
                    praw[wv][mt*16 + lhi*4 + q] = p[mt][q];
        }
        __syncthreads();
        if (tid < 64)
            rawv[brn][tid] = b3[0] + praw[0][tid] + praw[1][tid] + praw[2][tid] + praw[3][tid];
        __syncthreads();
    }

    if (tid < 64) {
        int row = row0 + tid;
        float T10 = 0.1f + 4.9f*fsigmoid(rawv[0][tid]);
        float M0  = 10000.0f*fsigmoid(rawv[1][tid]);
        Es[tid]  = __expf(-TR[row]/T10);
        M0s[tid] = M0;
        out[(size_t)B_TOT*T_LEN + row]         = T10;
        out[(size_t)B_TOT*T_LEN + B_TOT + row] = M0;
    }
    __syncthreads();
    for (int i = tid; i < 64*T_LEN; i += 256) {
        int rr = i / T_LEN, t = i - rr*T_LEN;
        int row = row0 + rr;
        float fa = FA[row*T_LEN + t];
        float s = __sinf(fa), c = __cosf(fa);
        float Ev = Es[rr];
        out[row*T_LEN + t] = (1.0f - Ev)*s*frcp(1.0f - c*Ev)*M0s[rr];
    }
}

extern "C" void kernel_launch(void* const* d_in, const int* in_sizes, int n_in,
                              void* d_out, int out_size, void* d_ws, size_t ws_size,
                              hipStream_t stream) {
    const float* Xin = (const float*)d_in[0];
    const float* FA  = (const float*)d_in[1];
    const float* TR  = (const float*)d_in[4];
    const float* Wih = (const float*)d_in[5];
    const float* Whh = (const float*)d_in[6];
    const float* bih = (const float*)d_in[7];
    const float* bhh = (const float*)d_in[8];
    const float* swT = (const float*)d_in[9];
    const float* swM = (const float*)d_in[10];
    const float* TW1 = (const float*)d_in[11]; const float* Tb1 = (const float*)d_in[12];
    const float* TW2 = (const float*)d_in[13]; const float* Tb2 = (const float*)d_in[14];
    const float* TW3 = (const float*)d_in[15]; const float* Tb3 = (const float*)d_in[16];
    const float* MW1 = (const float*)d_in[17]; const float* Mb1 = (const float*)d_in[18];
    const float* MW2 = (const float*)d_in[19]; const float* Mb2 = (const float*)d_in[20];
    const float* MW3 = (const float*)d_in[21]; const float* Mb3 = (const float*)d_in[22];
    float* out = (float*)d_out;

    float* hT = (float*)d_ws;
    float* hM = hT + (size_t)B_TOT*HD;

    gru_attn_mfma<<<B_TOT/64, 256, 0, stream>>>(Xin, FA, Wih, Whh, bih, bhh,
                                                swT, swM, hT, hM);
    mlp_mfma<<<B_TOT/64, 256, 0, stream>>>(hT, hM,
                                           TW1, Tb1, TW2, Tb2, TW3, Tb3,
                                           MW1, Mb1, MW2, Mb2, MW3, Mb3,
                                           FA, TR, out);
}

// Round 5
// 310.561 us; speedup vs baseline: 3.5739x; 3.5739x over previous
//
#include <hip/hip_runtime.h>

#define B_TOT 65536
#define T_LEN 34
#define HD 64
#define LOG2E 1.44269504088896340736f

typedef __attribute__((ext_vector_type(8))) short short8b;
typedef __attribute__((ext_vector_type(4))) short short4b;
typedef __attribute__((ext_vector_type(4))) float f32x4;

__device__ __forceinline__ float frcp(float x){ return __builtin_amdgcn_rcpf(x); }
__device__ __forceinline__ float fexp2(float x){ return __builtin_amdgcn_exp2f(x); }
__device__ __forceinline__ float fsigmoid(float x){ return frcp(1.0f+__expf(-x)); }
__device__ __forceinline__ float felu(float x){ return x>0.0f ? x : (__expf(x)-1.0f); }

__device__ __forceinline__ unsigned short f2bf_rne(float f){
    unsigned int u = __float_as_uint(f);
    u += 0x7FFFu + ((u >> 16) & 1u);
    return (unsigned short)(u >> 16);
}
__device__ __forceinline__ float bf2f(unsigned short h){
    return __uint_as_float(((unsigned int)h) << 16);
}
__device__ __forceinline__ unsigned short f2bf_fast(float f){
    unsigned int u = __float_as_uint(f);
    return (unsigned short)((u + 0x8000u) >> 16);
}
__device__ __forceinline__ void split8(const float4& a, const float4& b,
                                       short8b& hi, short8b& lo){
    float f[8] = {a.x,a.y,a.z,a.w,b.x,b.y,b.z,b.w};
    #pragma unroll
    for (int i = 0; i < 8; ++i){
        unsigned short h = f2bf_rne(f[i]);
        hi[i] = (short)h;
        lo[i] = (short)f2bf_rne(f[i] - bf2f(h));
    }
}

// ---------------- Kernel A: forward-fill + GRU (MFMA) + attention pooling ----------------
// 4 waves/block, 16 rows/wave. 13 B-tiles: 12 gate tiles (Whh pre-scaled by
// -log2e for r,z and +2log2e for n; bias folded into MFMA C-init) + 1 score
// tile (cols 0,1 = log2e*swT, log2e*swM). Gates use raw v_exp_f32/v_rcp_f32.
// NOTE: no waves/EU hint — __launch_bounds__(256,3) forced whole-array scratch
// demotion (VGPR 168->84, 2.2GB scratch fetch) in round 4.
__global__ __launch_bounds__(256)
void gru_attn_mfma(const float* __restrict__ Xin, const float* __restrict__ FA,
                   const float* __restrict__ Wih, const float* __restrict__ Whh,
                   const float* __restrict__ bih, const float* __restrict__ bhh,
                   const float* __restrict__ swT, const float* __restrict__ swM,
                   float* __restrict__ hT_out, float* __restrict__ hM_out)
{
    __shared__ __align__(16) unsigned short WF[26*512];   // 26 KB
    __shared__ __align__(16) unsigned short HL[4][1024];  // 8 KB
    __shared__ __align__(8)  float XF[4][16][T_LEN][2];   // 17 KB

    const int tid  = threadIdx.x;
    const int lane = tid & 63;
    const int wv   = tid >> 6;
    const int l16  = lane & 15;
    const int lhi  = lane >> 4;

    // ---- stage B-fragments (frag f: ks=f/13, nt=f%13) ----
    for (int f = wv; f < 26; f += 4) {
        int ks = f / 13, nt = f % 13;
        int k0 = ks*32 + lhi*8;
        unsigned short* dst = &WF[f*512 + lane*8];
        if (nt < 12) {
            int u  = nt*16 + l16;
            float scale = (nt < 8) ? -LOG2E : 2.0f*LOG2E;
            const float4 w0 = *reinterpret_cast<const float4*>(&Whh[u*64 + k0]);
            const float4 w1 = *reinterpret_cast<const float4*>(&Whh[u*64 + k0 + 4]);
            dst[0]=f2bf_rne(w0.x*scale); dst[1]=f2bf_rne(w0.y*scale);
            dst[2]=f2bf_rne(w0.z*scale); dst[3]=f2bf_rne(w0.w*scale);
            dst[4]=f2bf_rne(w1.x*scale); dst[5]=f2bf_rne(w1.y*scale);
            dst[6]=f2bf_rne(w1.z*scale); dst[7]=f2bf_rne(w1.w*scale);
        } else {
            const float* src = (l16 == 1) ? swM : swT;
            #pragma unroll
            for (int j = 0; j < 8; ++j)
                dst[j] = (l16 < 2) ? f2bf_rne(src[k0+j]*LOG2E) : (unsigned short)0;
        }
    }

    #pragma unroll
    for (int i = 0; i < 16; ++i) HL[wv][i*64 + lane] = 0;

    const int rowbase = blockIdx.x*64 + wv*16;

    // ---- forward fill (segmented LOCF) via lane prefix-max ----
    for (int rr = 0; rr < 16; ++rr) {
        int row = rowbase + rr;
        float X = 0.0f, fa = 0.0f; int idx = -1;
        if (lane < T_LEN) {
            X  = Xin[row*T_LEN + lane];
            fa = FA [row*T_LEN + lane];
            if (X != 0.0f) idx = lane;
        }
        #pragma unroll
        for (int off = 1; off < 64; off <<= 1) {
            int v = __shfl_up(idx, off);
            if (lane >= off && v > idx) idx = v;
        }
        int gsrc = idx < 0 ? 0 : idx;
        float Xg = __shfl(X,  gsrc);
        float fg = __shfl(fa, gsrc);
        if (idx < 0) { Xg = 0.0f; fg = 0.0f; }
        if (lane < T_LEN) { XF[wv][rr][lane][0] = Xg; XF[wv][rr][lane][1] = fg; }
    }

    // ---- per-lane constants (pre-scaled for exp2) ----
    float wrx[4], wrf[4], wzx[4], wzf[4], wnx[4], wnf[4], bihn[4], biasD[12];
    #pragma unroll
    for (int nt = 0; nt < 4; ++nt) {
        int ul = nt*16 + l16;
        wrx[nt] = -LOG2E*Wih[ ul*2     ]; wrf[nt] = -LOG2E*Wih[ ul*2     +1];
        wzx[nt] = -LOG2E*Wih[(64+ul)*2 ]; wzf[nt] = -LOG2E*Wih[(64+ul)*2 +1];
        wnx[nt] = 2.0f*LOG2E*Wih[(128+ul)*2]; wnf[nt] = 2.0f*LOG2E*Wih[(128+ul)*2+1];
        bihn[nt] = 2.0f*LOG2E*bih[128+ul];
    }
    #pragma unroll
    for (int nt = 0; nt < 12; ++nt) {
        int u = nt*16 + l16;
        biasD[nt] = (nt < 8) ? -LOG2E*(bih[u] + bhh[u]) : 2.0f*LOG2E*bhh[u];
    }

    __syncthreads();

    const int swz   = (l16 & 7) << 3;
    const int aoff0 = l16*64 + ((     lhi*8) ^ swz);
    const int aoff1 = l16*64 + ((32 + lhi*8) ^ swz);
    const int bcast = lane & 48;

    // hoist loop-invariant score B-fragments into registers (8 VGPRs each)
    const short8b bS0 = *reinterpret_cast<const short8b*>(&WF[12*512 + lane*8]);
    const short8b bS1 = *reinterpret_cast<const short8b*>(&WF[25*512 + lane*8]);

    float hreg[4][4] = {};
    float numT[4][4] = {}, numM[4][4] = {};
    float denT[4]    = {}, denM[4]    = {};

    const unsigned short* HLr = HL[wv];
    unsigned short*       HLw = HL[wv];

    for (int t = 0; t < T_LEN; ++t) {
        short8b a0 = *reinterpret_cast<const short8b*>(&HLr[aoff0]);
        short8b a1 = *reinterpret_cast<const short8b*>(&HLr[aoff1]);
        // score tile first so pooling overlaps the gate MFMAs
        f32x4 accS = (f32x4){0.f,0.f,0.f,0.f};
        accS = __builtin_amdgcn_mfma_f32_16x16x32_bf16(a0, bS0, accS, 0,0,0);
        accS = __builtin_amdgcn_mfma_f32_16x16x32_bf16(a1, bS1, accS, 0,0,0);
        f32x4 acc[12];
        #pragma unroll
        for (int nt = 0; nt < 12; ++nt) {
            float b = biasD[nt];
            acc[nt] = (f32x4){b, b, b, b};
            acc[nt] = __builtin_amdgcn_mfma_f32_16x16x32_bf16(
                a0, *reinterpret_cast<const short8b*>(&WF[ nt     *512 + lane*8]), acc[nt], 0,0,0);
            acc[nt] = __builtin_amdgcn_mfma_f32_16x16x32_bf16(
                a1, *reinterpret_cast<const short8b*>(&WF[(13+nt)*512 + lane*8]), acc[nt], 0,0,0);
        }
        // pooling of h_{t-1} (the state entering this step) — skip t=0 (h=0 not an output)
        if (t) {
            #pragma unroll
            for (int q = 0; q < 4; ++q) {
                float e  = fexp2(accS[q]);
                float eT = __shfl(e, bcast);
                float eM = __shfl(e, bcast | 1);
                denT[q] += eT; denM[q] += eM;
                #pragma unroll
                for (int nt = 0; nt < 4; ++nt) {
                    numT[q][nt] = fmaf(eT, hreg[q][nt], numT[q][nt]);
                    numM[q][nt] = fmaf(eM, hreg[q][nt], numM[q][nt]);
                }
            }
        }
        // gates (pre-scaled: r,z use exp2(-L*x); n uses exp2(2L*v))
        #pragma unroll
        for (int q = 0; q < 4; ++q) {
            const int rloc = lhi*4 + q;
            const int rs   = (rloc & 7) << 3;
            float2 xf = *reinterpret_cast<const float2*>(&XF[wv][rloc][t][0]);
            float x = xf.x, fv = xf.y;
            #pragma unroll
            for (int nt = 0; nt < 4; ++nt) {
                float Sr = acc[nt][q], Sz = acc[nt+4][q], Sn = acc[nt+8][q];
                float ur = fmaf(wrx[nt], x, fmaf(wrf[nt], fv, Sr));
                float r  = frcp(1.0f + fexp2(ur));
                float uz = fmaf(wzx[nt], x, fmaf(wzf[nt], fv, Sz));
                float z  = frcp(1.0f + fexp2(uz));
                float xn = fmaf(wnx[nt], x, fmaf(wnf[nt], fv, bihn[nt]));
                float v  = fmaf(r, Sn, xn);
                float n  = fmaf(-2.0f, frcp(1.0f + fexp2(v)), 1.0f);
                float hn = fmaf(z, hreg[q][nt] - n, n);
                hreg[q][nt] = hn;
                HLw[rloc*64 + ((((nt<<4) + l16)) ^ rs)] = f2bf_fast(hn);
            }
        }
    }

    // ---- pool the final state h_{T-1} ----
    {
        short8b a0 = *reinterpret_cast<const short8b*>(&HLr[aoff0]);
        short8b a1 = *reinterpret_cast<const short8b*>(&HLr[aoff1]);
        f32x4 accS = (f32x4){0.f,0.f,0.f,0.f};
        accS = __builtin_amdgcn_mfma_f32_16x16x32_bf16(a0, bS0, accS, 0,0,0);
        accS = __builtin_amdgcn_mfma_f32_16x16x32_bf16(a1, bS1, accS, 0,0,0);
        #pragma unroll
        for (int q = 0; q < 4; ++q) {
            float e  = fexp2(accS[q]);
            float eT = __shfl(e, bcast);
            float eM = __shfl(e, bcast | 1);
            denT[q] += eT; denM[q] += eM;
            #pragma unroll
            for (int nt = 0; nt < 4; ++nt) {
                numT[q][nt] = fmaf(eT, hreg[q][nt], numT[q][nt]);
                numM[q][nt] = fmaf(eM, hreg[q][nt], numM[q][nt]);
            }
        }
    }

    #pragma unroll
    for (int q = 0; q < 4; ++q) {
        int row = rowbase + lhi*4 + q;
        float rT = frcp(denT[q]), rM = frcp(denM[q]);
        #pragma unroll
        for (int nt = 0; nt < 4; ++nt) {
            hT_out[row*HD + nt*16 + l16] = numT[q][nt]*rT;
            hM_out[row*HD + nt*16 + l16] = numM[q][nt]*rM;
        }
    }
}

// ---------------- Kernel B: MFMA MLP heads + T10/M0 + X_out ----------------
__global__ __launch_bounds__(256)
void mlp_mfma(const float* __restrict__ hT, const float* __restrict__ hM,
    const float* __restrict__ TW1, const float* __restrict__ Tb1,
    const float* __restrict__ TW2, const float* __restrict__ Tb2,
    const float* __restrict__ TW3, const float* __restrict__ Tb3,
    const float* __restrict__ MW1, const float* __restrict__ Mb1,
    const float* __restrict__ MW2, const float* __restrict__ Mb2,
    const float* __restrict__ MW3, const float* __restrict__ Mb3,
    const float* __restrict__ FA, const float* __restrict__ TR,
    float* __restrict__ out)
{
    __shared__ __align__(16) unsigned short xh[2*64*64];
    __shared__ __align__(16) unsigned short h1s[64*256];
    __shared__ float praw[4][64];
    __shared__ float rawv[2][64];
    __shared__ float Es[64], M0s[64];

    const int tid  = threadIdx.x;
    const int lane = tid & 63;
    const int wv   = tid >> 6;
    const int l16  = lane & 15;
    const int lhi  = lane >> 4;
    const int row0 = blockIdx.x*64;

    {
        int r  = tid >> 2;
        int k0 = (tid & 3) * 16;
        int rx = r & 7;
        const float* pT = &hT[(row0+r)*64 + k0];
        const float* pM = &hM[(row0+r)*64 + k0];
        #pragma unroll
        for (int j = 0; j < 4; ++j) {
            float4 vT = *reinterpret_cast<const float4*>(pT + 4*j);
            float4 vM = *reinterpret_cast<const float4*>(pM + 4*j);
            int kk = k0 + 4*j;
            int ad = r*64 + ((((kk>>3) ^ rx))<<3) + (kk&7);
            short4b sT = { (short)f2bf_rne(vT.x), (short)f2bf_rne(vT.y),
                           (short)f2bf_rne(vT.z), (short)f2bf_rne(vT.w) };
            short4b sM = { (short)f2bf_rne(vM.x), (short)f2bf_rne(vM.y),
                           (short)f2bf_rne(vM.z), (short)f2bf_rne(vM.w) };
            *reinterpret_cast<short4b*>(&xh[ad])        = sT;
            *reinterpret_cast<short4b*>(&xh[4096 + ad]) = sM;
        }
        for (int i = tid; i < 64*24; i += 256) {
            int rr = i / 24, kk = 200 + i % 24;
            h1s[rr*256 + ((((kk>>3) ^ (rr&7)))<<3) + (kk&7)] = 0;
        }
    }
    __syncthreads();

    for (int brn = 0; brn < 2; ++brn) {
        const float* W1 = brn ? MW1 : TW1; const float* b1 = brn ? Mb1 : Tb1;
        const float* W2 = brn ? MW2 : TW2; const float* b2 = brn ? Mb2 : Tb2;
        const float* W3 = brn ? MW3 : TW3; const float* b3 = brn ? Mb3 : Tb3;

        for (int s = 0; s < 4; ++s) {
            int nt = wv + 4*s;
            if (nt > 12) break;
            int n  = nt*16 + l16;
            int nc = n < 200 ? n : 199;
            float bv = b1[nc];
            f32x4 acc[4];
            #pragma unroll
            for (int mt = 0; mt < 4; ++mt) acc[mt] = (f32x4){bv,bv,bv,bv};
            #pragma unroll
            for (int ks = 0; ks < 2; ++ks) {
                int k0 = ks*32 + lhi*8;
                const float* wp = &W1[nc*64 + k0];
                float4 w0 = *reinterpret_cast<const float4*>(wp);
                float4 w1 = *reinterpret_cast<const float4*>(wp + 4);
                short8b bh, bl;
                split8(w0, w1, bh, bl);
                #pragma unroll
                for (int mt = 0; mt < 4; ++mt) {
                    int rr = mt*16 + l16;
                    short8b a = *reinterpret_cast<const short8b*>(
                        &xh[brn*4096 + rr*64 + ((((k0>>3) ^ (rr&7)))<<3)]);
                    acc[mt] = __builtin_amdgcn_mfma_f32_16x16x32_bf16(a, bh, acc[mt], 0,0,0);
                    acc[mt] = __builtin_amdgcn_mfma_f32_16x16x32_bf16(a, bl, acc[mt], 0,0,0);
                }
            }
            if (n < 200) {
                #pragma unroll
                for (int mt = 0; mt < 4; ++mt) {
                    #pragma unroll
                    for (int q = 0; q < 4; ++q) {
                        int rr = mt*16 + lhi*4 + q;
                        h1s[rr*256 + ((((n>>3) ^ (rr&7)))<<3) + (n&7)] =
                            f2bf_rne(felu(acc[mt][q]));
                    }
                }
            }
        }
        __syncthreads();

        float p[4][4] = {};
        for (int s = 0; s < 4; ++s) {
            int nt = wv + 4*s;
            if (nt > 12) break;
            int n  = nt*16 + l16;
            int nc = n < 200 ? n : 199;
            float w3v = (n < 200) ? W3[nc] : 0.0f;
            float bv = b2[nc];
            f32x4 acc[4];
            #pragma unroll
            for (int mt = 0; mt < 4; ++mt) acc[mt] = (f32x4){bv,bv,bv,bv};
            for (int ks = 0; ks < 7; ++ks) {
                int k0 = ks*32 + lhi*8;
                short8b bh, bl;
                if (k0 + 8 <= 200) {
                    const float* wp = &W2[nc*200 + k0];
                    float4 w0 = *reinterpret_cast<const float4*>(wp);
                    float4 w1 = *reinterpret_cast<const float4*>(wp + 4);
                    split8(w0, w1, bh, bl);
                } else {
                    #pragma unroll
                    for (int i = 0; i < 8; ++i) { bh[i] = 0; bl[i] = 0; }
                }
                #pragma unroll
                for (int mt = 0; mt < 4; ++mt) {
                    int rr = mt*16 + l16;
                    short8b a = *reinterpret_cast<const short8b*>(
                        &h1s[rr*256 + ((((k0>>3) ^ (rr&7)))<<3)]);
                    acc[mt] = __builtin_amdgcn_mfma_f32_16x16x32_bf16(a, bh, acc[mt], 0,0,0);
                    acc[mt] = __builtin_amdgcn_mfma_f32_16x16x32_bf16(a, bl, acc[mt], 0,0,0);
                }
            }
            #pragma unroll
            for (int mt = 0; mt < 4; ++mt)
                #pragma unroll
                for (int q = 0; q < 4; ++q)
                    p[mt][q] = fmaf(w3v, felu(acc[mt][q]), p[mt][q]);
        }
        #pragma unroll
        for (int off = 1; off < 16; off <<= 1) {
            #pragma unroll
            for (int mt = 0; mt < 4; ++mt)
                #pragma unroll
                for (int q = 0; q < 4; ++q)
                    p[mt][q] += __shfl_xor(p[mt][q], off);
        }
        if (l16 == 0) {
            #pragma unroll
            for (int mt = 0; mt < 4; ++mt)
                #pragma unroll
                for (int q = 0; q < 4; ++q)
                    praw[wv][mt*16 + lhi*4 + q] = p[mt][q];
        }
        __syncthreads();
        if (tid < 64)
            rawv[brn][tid] = b3[0] + praw[0][tid] + praw[1][tid] + praw[2][tid] + praw[3][tid];
        __syncthreads();
    }

    if (tid < 64) {
        int row = row0 + tid;
        float T10 = 0.1f + 4.9f*fsigmoid(rawv[0][tid]);
        float M0  = 10000.0f*fsigmoid(rawv[1][tid]);
        Es[tid]  = __expf(-TR[row]/T10);
        M0s[tid] = M0;
        out[(size_t)B_TOT*T_LEN + row]         = T10;
        out[(size_t)B_TOT*T_LEN + B_TOT + row] = M0;
    }
    __syncthreads();
    for (int i = tid; i < 64*T_LEN; i += 256) {
        int rr = i / T_LEN, t = i - rr*T_LEN;
        int row = row0 + rr;
        float fa = FA[row*T_LEN + t];
        float s = __sinf(fa), c = __cosf(fa);
        float Ev = Es[rr];
        out[row*T_LEN + t] = (1.0f - Ev)*s*frcp(1.0f - c*Ev)*M0s[rr];
    }
}

extern "C" void kernel_launch(void* const* d_in, const int* in_sizes, int n_in,
                              void* d_out, int out_size, void* d_ws, size_t ws_size,
                              hipStream_t stream) {
    const float* Xin = (const float*)d_in[0];
    const float* FA  = (const float*)d_in[1];
    const float* TR  = (const float*)d_in[4];
    const float* Wih = (const float*)d_in[5];
    const float* Whh = (const float*)d_in[6];
    const float* bih = (const float*)d_in[7];
    const float* bhh = (const float*)d_in[8];
    const float* swT = (const float*)d_in[9];
    const float* swM = (const float*)d_in[10];
    const float* TW1 = (const float*)d_in[11]; const float* Tb1 = (const float*)d_in[12];
    const float* TW2 = (const float*)d_in[13]; const float* Tb2 = (const float*)d_in[14];
    const float* TW3 = (const float*)d_in[15]; const float* Tb3 = (const float*)d_in[16];
    const float* MW1 = (const float*)d_in[17]; const float* Mb1 = (const float*)d_in[18];
    const float* MW2 = (const float*)d_in[19]; const float* Mb2 = (const float*)d_in[20];
    const float* MW3 = (const float*)d_in[21]; const float* Mb3 = (const float*)d_in[22];
    float* out = (float*)d_out;

    float* hT = (float*)d_ws;
    float* hM = hT + (size_t)B_TOT*HD;

    gru_attn_mfma<<<B_TOT/64, 256, 0, stream>>>(Xin, FA, Wih, Whh, bih, bhh,
                                                swT, swM, hT, hM);
    mlp_mfma<<<B_TOT/64, 256, 0, stream>>>(hT, hM,
                                           TW1, Tb1, TW2, Tb2, TW3, Tb3,
                                           MW1, Mb1, MW2, Mb2, MW3, Mb3,
                                           FA, TR, out);
}

// Round 6
// 294.254 us; speedup vs baseline: 3.7720x; 1.0554x over previous
//
#include <hip/hip_runtime.h>

#define B_TOT 65536
#define T_LEN 34
#define HD 64
#define LOG2E 1.44269504088896340736f

typedef __attribute__((ext_vector_type(8))) short short8b;
typedef __attribute__((ext_vector_type(4))) short short4b;
typedef __attribute__((ext_vector_type(4))) float f32x4;
typedef __attribute__((ext_vector_type(4))) unsigned int u32x4;

__device__ __forceinline__ float frcp(float x){ return __builtin_amdgcn_rcpf(x); }
__device__ __forceinline__ float fexp2(float x){ return __builtin_amdgcn_exp2f(x); }
__device__ __forceinline__ float fsigmoid(float x){ return frcp(1.0f+__expf(-x)); }
__device__ __forceinline__ float felu(float x){ return x>0.0f ? x : (__expf(x)-1.0f); }

__device__ __forceinline__ unsigned short f2bf_rne(float f){
    unsigned int u = __float_as_uint(f);
    u += 0x7FFFu + ((u >> 16) & 1u);
    return (unsigned short)(u >> 16);
}
__device__ __forceinline__ float bf2f(unsigned short h){
    return __uint_as_float(((unsigned int)h) << 16);
}
__device__ __forceinline__ unsigned short f2bf_fast(float f){
    unsigned int u = __float_as_uint(f);
    return (unsigned short)((u + 0x8000u) >> 16);
}
__device__ __forceinline__ void split8(const float4& a, const float4& b,
                                       short8b& hi, short8b& lo){
    float f[8] = {a.x,a.y,a.z,a.w,b.x,b.y,b.z,b.w};
    #pragma unroll
    for (int i = 0; i < 8; ++i){
        unsigned short h = f2bf_rne(f[i]);
        hi[i] = (short)h;
        lo[i] = (short)f2bf_rne(f[i] - bf2f(h));
    }
}
// fragment whose first dword is w, rest zero
__device__ __forceinline__ short8b frag_from_word(unsigned int w){
    u32x4 v = {w, 0u, 0u, 0u};
    return __builtin_bit_cast(short8b, v);
}

// ---------------- Kernel A: forward-fill + GRU (MFMA, input-proj folded) ----------------
// 4 waves/block, 16 rows/wave. Per t-step, per unit-group g (0..3):
//   acc_r  = -L*(bih_r+bhh_r) + (-L*Whh_r)·h + (-L*Wih_r)·[x,fv]     (3 MFMA)
//   acc_z  = same (3 MFMA)
//   acc_nh = 2L*bhh_n + (2L*Whh_n)·h                                  (2 MFMA)
//   acc_nx = 2L*bih_n + (2L*Wih_n)·[x,fv]                             (1 MFMA)
// then gates lane-locally (r=rcp(1+exp2(acc_r)), v=fma(r,acc_nh,acc_nx), ...).
// Score tile (2 MFMA) feeds online softmax pooling. LDS exactly 40 KB.
__global__ __launch_bounds__(256)
void gru_attn_mfma(const float* __restrict__ Xin, const float* __restrict__ FA,
                   const float* __restrict__ Wih, const float* __restrict__ Whh,
                   const float* __restrict__ bih, const float* __restrict__ bhh,
                   const float* __restrict__ swT, const float* __restrict__ swM,
                   float* __restrict__ hT_out, float* __restrict__ hM_out)
{
    __shared__ __align__(16) unsigned short WF[24*512];   // 24 KB gate B-tiles
    __shared__ __align__(16) unsigned short HL[4][1024];  // 8 KB  h tiles (bf16, swizzled)
    __shared__ unsigned int XF[32*64];                    // 8 KB  [t<32][row] packed (x,fv) bf16x2

    const int tid  = threadIdx.x;
    const int lane = tid & 63;
    const int wv   = tid >> 6;
    const int l16  = lane & 15;
    const int lhi  = lane >> 4;

    // ---- stage Whh B-fragments (tile f = ks*12+nt) ----
    for (int f = wv; f < 24; f += 4) {
        int ks = f / 12, nt = f % 12;
        int u  = nt*16 + l16;
        int k0 = ks*32 + lhi*8;
        float scale = (nt < 8) ? -LOG2E : 2.0f*LOG2E;
        const float4 w0 = *reinterpret_cast<const float4*>(&Whh[u*64 + k0]);
        const float4 w1 = *reinterpret_cast<const float4*>(&Whh[u*64 + k0 + 4]);
        unsigned short* dst = &WF[f*512 + lane*8];
        dst[0]=f2bf_rne(w0.x*scale); dst[1]=f2bf_rne(w0.y*scale);
        dst[2]=f2bf_rne(w0.z*scale); dst[3]=f2bf_rne(w0.w*scale);
        dst[4]=f2bf_rne(w1.x*scale); dst[5]=f2bf_rne(w1.y*scale);
        dst[6]=f2bf_rne(w1.z*scale); dst[7]=f2bf_rne(w1.w*scale);
    }

    #pragma unroll
    for (int i = 0; i < 16; ++i) HL[wv][i*64 + lane] = 0;

    // ---- score B-fragments in registers (col0 = L*swT, col1 = L*swM) ----
    short8b bS0, bS1;
    {
        const float* src = (l16 == 1) ? swM : swT;
        #pragma unroll
        for (int j = 0; j < 8; ++j) {
            bS0[j] = (l16 < 2) ? (short)f2bf_rne(src[     lhi*8 + j]*LOG2E) : (short)0;
            bS1[j] = (l16 < 2) ? (short)f2bf_rne(src[32 + lhi*8 + j]*LOG2E) : (short)0;
        }
    }

    // ---- ext B-words (Wih columns, scaled) + biases ----
    unsigned int wext[12];
    float biasD[12], biasX[4];
    #pragma unroll
    for (int nt = 0; nt < 12; ++nt) {
        int u = nt*16 + l16;
        float s = (nt < 8) ? -LOG2E : 2.0f*LOG2E;
        unsigned int pk = (unsigned int)f2bf_rne(s*Wih[u*2])
                        | ((unsigned int)f2bf_rne(s*Wih[u*2+1]) << 16);
        wext[nt] = (lhi == 0) ? pk : 0u;
        biasD[nt] = (nt < 8) ? -LOG2E*(bih[u] + bhh[u]) : 2.0f*LOG2E*bhh[u];
        if (nt >= 8) biasX[nt-8] = 2.0f*LOG2E*bih[u];
    }

    const int rowbase = blockIdx.x*64 + wv*16;

    // ---- forward fill (segmented LOCF); lane = time; pack (x,fv) as bf16x2 ----
    unsigned int xt32 = 0, xt33 = 0;
    for (int rr = 0; rr < 16; ++rr) {
        int row = rowbase + rr;
        float X = 0.0f, fa = 0.0f; int idx = -1;
        if (lane < T_LEN) {
            X  = Xin[row*T_LEN + lane];
            fa = FA [row*T_LEN + lane];
            if (X != 0.0f) idx = lane;
        }
        #pragma unroll
        for (int off = 1; off < 64; off <<= 1) {
            int v = __shfl_up(idx, off);
            if (lane >= off && v > idx) idx = v;
        }
        int gsrc = idx < 0 ? 0 : idx;
        float Xg = __shfl(X,  gsrc);
        float fg = __shfl(fa, gsrc);
        if (idx < 0) { Xg = 0.0f; fg = 0.0f; }
        unsigned int p = (unsigned int)f2bf_rne(Xg) | ((unsigned int)f2bf_rne(fg) << 16);
        if (lane < 32) XF[lane*64 + wv*16 + rr] = p;
        unsigned int v32 = __shfl(p, 32), v33 = __shfl(p, 33);
        if (l16 == rr) { xt32 = v32; xt33 = v33; }
    }

    __syncthreads();   // WF/XF visible

    const int swz   = (l16 & 7) << 3;
    const int aoff0 = l16*64 + ((     lhi*8) ^ swz);
    const int aoff1 = l16*64 + ((32 + lhi*8) ^ swz);
    const int bcast = lane & 48;
    const int xfidx = wv*16 + l16;

    float2 hreg2[4][2];
    float2 numT2[4][2], numM2[4][2];
    float  denT[4] = {}, denM[4] = {};
    #pragma unroll
    for (int q = 0; q < 4; ++q)
        #pragma unroll
        for (int j = 0; j < 2; ++j) {
            hreg2[q][j] = make_float2(0.f, 0.f);
            numT2[q][j] = make_float2(0.f, 0.f);
            numM2[q][j] = make_float2(0.f, 0.f);
        }

    const unsigned short* HLr = HL[wv];
    unsigned short*       HLw = HL[wv];
    const unsigned short* WFl = &WF[lane*8];

    for (int t = 0; t < T_LEN; ++t) {
        short8b a0 = *reinterpret_cast<const short8b*>(&HLr[aoff0]);
        short8b a1 = *reinterpret_cast<const short8b*>(&HLr[aoff1]);
        unsigned int xw = (t < 32) ? XF[t*64 + xfidx] : ((t == 32) ? xt32 : xt33);
        short8b aext = frag_from_word((lhi == 0) ? xw : 0u);

        // score tile first so pooling overlaps gate MFMAs
        f32x4 accS = (f32x4){0.f,0.f,0.f,0.f};
        accS = __builtin_amdgcn_mfma_f32_16x16x32_bf16(a0, bS0, accS, 0,0,0);
        accS = __builtin_amdgcn_mfma_f32_16x16x32_bf16(a1, bS1, accS, 0,0,0);

        if (t) {   // pool h_{t-1}
            #pragma unroll
            for (int q = 0; q < 4; ++q) {
                float e  = fexp2(accS[q]);
                float eT = __shfl(e, bcast);
                float eM = __shfl(e, bcast | 1);
                denT[q] += eT; denM[q] += eM;
                #pragma unroll
                for (int j = 0; j < 2; ++j) {
                    numT2[q][j].x = fmaf(eT, hreg2[q][j].x, numT2[q][j].x);
                    numT2[q][j].y = fmaf(eT, hreg2[q][j].y, numT2[q][j].y);
                    numM2[q][j].x = fmaf(eM, hreg2[q][j].x, numM2[q][j].x);
                    numM2[q][j].y = fmaf(eM, hreg2[q][j].y, numM2[q][j].y);
                }
            }
        }

        // unit-group trios: MFMAs then gates immediately (bounded live acc)
        #pragma unroll
        for (int g = 0; g < 4; ++g) {
            float br = biasD[g], bz = biasD[g+4], bnh = biasD[g+8], bnx = biasX[g];
            f32x4 ar  = (f32x4){br,br,br,br};
            f32x4 az  = (f32x4){bz,bz,bz,bz};
            f32x4 anh = (f32x4){bnh,bnh,bnh,bnh};
            f32x4 anx = (f32x4){bnx,bnx,bnx,bnx};
            ar  = __builtin_amdgcn_mfma_f32_16x16x32_bf16(a0, *reinterpret_cast<const short8b*>(WFl + (g   )*512), ar , 0,0,0);
            ar  = __builtin_amdgcn_mfma_f32_16x16x32_bf16(a1, *reinterpret_cast<const short8b*>(WFl + (12+g)*512), ar , 0,0,0);
            ar  = __builtin_amdgcn_mfma_f32_16x16x32_bf16(aext, frag_from_word(wext[g]),   ar , 0,0,0);
            az  = __builtin_amdgcn_mfma_f32_16x16x32_bf16(a0, *reinterpret_cast<const short8b*>(WFl + (g+4 )*512), az , 0,0,0);
            az  = __builtin_amdgcn_mfma_f32_16x16x32_bf16(a1, *reinterpret_cast<const short8b*>(WFl + (16+g)*512), az , 0,0,0);
            az  = __builtin_amdgcn_mfma_f32_16x16x32_bf16(aext, frag_from_word(wext[g+4]), az , 0,0,0);
            anh = __builtin_amdgcn_mfma_f32_16x16x32_bf16(a0, *reinterpret_cast<const short8b*>(WFl + (g+8 )*512), anh, 0,0,0);
            anh = __builtin_amdgcn_mfma_f32_16x16x32_bf16(a1, *reinterpret_cast<const short8b*>(WFl + (20+g)*512), anh, 0,0,0);
            anx = __builtin_amdgcn_mfma_f32_16x16x32_bf16(aext, frag_from_word(wext[g+8]), anx, 0,0,0);
            #pragma unroll
            for (int q = 0; q < 4; ++q) {
                float r  = frcp(1.0f + fexp2(ar[q]));
                float z  = frcp(1.0f + fexp2(az[q]));
                float v  = fmaf(r, anh[q], anx[q]);
                float n  = fmaf(-2.0f, frcp(1.0f + fexp2(v)), 1.0f);
                float h  = (g & 1) ? hreg2[q][g>>1].y : hreg2[q][g>>1].x;
                float hn = fmaf(z, h - n, n);
                if (g & 1) hreg2[q][g>>1].y = hn; else hreg2[q][g>>1].x = hn;
                int rloc = lhi*4 + q;
                HLw[rloc*64 + (((g<<4) + l16) ^ ((rloc & 7) << 3))] = f2bf_fast(hn);
            }
        }
    }

    // ---- pool final state h_{T-1} ----
    {
        short8b a0 = *reinterpret_cast<const short8b*>(&HLr[aoff0]);
        short8b a1 = *reinterpret_cast<const short8b*>(&HLr[aoff1]);
        f32x4 accS = (f32x4){0.f,0.f,0.f,0.f};
        accS = __builtin_amdgcn_mfma_f32_16x16x32_bf16(a0, bS0, accS, 0,0,0);
        accS = __builtin_amdgcn_mfma_f32_16x16x32_bf16(a1, bS1, accS, 0,0,0);
        #pragma unroll
        for (int q = 0; q < 4; ++q) {
            float e  = fexp2(accS[q]);
            float eT = __shfl(e, bcast);
            float eM = __shfl(e, bcast | 1);
            denT[q] += eT; denM[q] += eM;
            #pragma unroll
            for (int j = 0; j < 2; ++j) {
                numT2[q][j].x = fmaf(eT, hreg2[q][j].x, numT2[q][j].x);
                numT2[q][j].y = fmaf(eT, hreg2[q][j].y, numT2[q][j].y);
                numM2[q][j].x = fmaf(eM, hreg2[q][j].x, numM2[q][j].x);
                numM2[q][j].y = fmaf(eM, hreg2[q][j].y, numM2[q][j].y);
            }
        }
    }

    #pragma unroll
    for (int q = 0; q < 4; ++q) {
        int row = rowbase + lhi*4 + q;
        float rT = frcp(denT[q]), rM = frcp(denM[q]);
        #pragma unroll
        for (int j = 0; j < 2; ++j) {
            hT_out[row*HD + (2*j  )*16 + l16] = numT2[q][j].x*rT;
            hT_out[row*HD + (2*j+1)*16 + l16] = numT2[q][j].y*rT;
            hM_out[row*HD + (2*j  )*16 + l16] = numM2[q][j].x*rM;
            hM_out[row*HD + (2*j+1)*16 + l16] = numM2[q][j].y*rM;
        }
    }
}

// ---------------- Kernel B: MFMA MLP heads + T10/M0 + X_out (unchanged) ----------------
__global__ __launch_bounds__(256)
void mlp_mfma(const float* __restrict__ hT, const float* __restrict__ hM,
    const float* __restrict__ TW1, const float* __restrict__ Tb1,
    const float* __restrict__ TW2, const float* __restrict__ Tb2,
    const float* __restrict__ TW3, const float* __restrict__ Tb3,
    const float* __restrict__ MW1, const float* __restrict__ Mb1,
    const float* __restrict__ MW2, const float* __restrict__ Mb2,
    const float* __restrict__ MW3, const float* __restrict__ Mb3,
    const float* __restrict__ FA, const float* __restrict__ TR,
    float* __restrict__ out)
{
    __shared__ __align__(16) unsigned short xh[2*64*64];
    __shared__ __align__(16) unsigned short h1s[64*256];
    __shared__ float praw[4][64];
    __shared__ float rawv[2][64];
    __shared__ float Es[64], M0s[64];

    const int tid  = threadIdx.x;
    const int lane = tid & 63;
    const int wv   = tid >> 6;
    const int l16  = lane & 15;
    const int lhi  = lane >> 4;
    const int row0 = blockIdx.x*64;

    {
        int r  = tid >> 2;
        int k0 = (tid & 3) * 16;
        int rx = r & 7;
        const float* pT = &hT[(row0+r)*64 + k0];
        const float* pM = &hM[(row0+r)*64 + k0];
        #pragma unroll
        for (int j = 0; j < 4; ++j) {
            float4 vT = *reinterpret_cast<const float4*>(pT + 4*j);
            float4 vM = *reinterpret_cast<const float4*>(pM + 4*j);
            int kk = k0 + 4*j;
            int ad = r*64 + ((((kk>>3) ^ rx))<<3) + (kk&7);
            short4b sT = { (short)f2bf_rne(vT.x), (short)f2bf_rne(vT.y),
                           (short)f2bf_rne(vT.z), (short)f2bf_rne(vT.w) };
            short4b sM = { (short)f2bf_rne(vM.x), (short)f2bf_rne(vM.y),
                           (short)f2bf_rne(vM.z), (short)f2bf_rne(vM.w) };
            *reinterpret_cast<short4b*>(&xh[ad])        = sT;
            *reinterpret_cast<short4b*>(&xh[4096 + ad]) = sM;
        }
        for (int i = tid; i < 64*24; i += 256) {
            int rr = i / 24, kk = 200 + i % 24;
            h1s[rr*256 + ((((kk>>3) ^ (rr&7)))<<3) + (kk&7)] = 0;
        }
    }
    __syncthreads();

    for (int brn = 0; brn < 2; ++brn) {
        const float* W1 = brn ? MW1 : TW1; const float* b1 = brn ? Mb1 : Tb1;
        const float* W2 = brn ? MW2 : TW2; const float* b2 = brn ? Mb2 : Tb2;
        const float* W3 = brn ? MW3 : TW3; const float* b3 = brn ? Mb3 : Tb3;

        for (int s = 0; s < 4; ++s) {
            int nt = wv + 4*s;
            if (nt > 12) break;
            int n  = nt*16 + l16;
            int nc = n < 200 ? n : 199;
            float bv = b1[nc];
            f32x4 acc[4];
            #pragma unroll
            for (int mt = 0; mt < 4; ++mt) acc[mt] = (f32x4){bv,bv,bv,bv};
            #pragma unroll
            for (int ks = 0; ks < 2; ++ks) {
                int k0 = ks*32 + lhi*8;
                const float* wp = &W1[nc*64 + k0];
                float4 w0 = *reinterpret_cast<const float4*>(wp);
                float4 w1 = *reinterpret_cast<const float4*>(wp + 4);
                short8b bh, bl;
                split8(w0, w1, bh, bl);
                #pragma unroll
                for (int mt = 0; mt < 4; ++mt) {
                    int rr = mt*16 + l16;
                    short8b a = *reinterpret_cast<const short8b*>(
                        &xh[brn*4096 + rr*64 + ((((k0>>3) ^ (rr&7)))<<3)]);
                    acc[mt] = __builtin_amdgcn_mfma_f32_16x16x32_bf16(a, bh, acc[mt], 0,0,0);
                    acc[mt] = __builtin_amdgcn_mfma_f32_16x16x32_bf16(a, bl, acc[mt], 0,0,0);
                }
            }
            if (n < 200) {
                #pragma unroll
                for (int mt = 0; mt < 4; ++mt) {
                    #pragma unroll
                    for (int q = 0; q < 4; ++q) {
                        int rr = mt*16 + lhi*4 + q;
                        h1s[rr*256 + ((((n>>3) ^ (rr&7)))<<3) + (n&7)] =
                            f2bf_rne(felu(acc[mt][q]));
                    }
                }
            }
        }
        __syncthreads();

        float p[4][4] = {};
        for (int s = 0; s < 4; ++s) {
            int nt = wv + 4*s;
            if (nt > 12) break;
            int n  = nt*16 + l16;
            int nc = n < 200 ? n : 199;
            float w3v = (n < 200) ? W3[nc] : 0.0f;
            float bv = b2[nc];
            f32x4 acc[4];
            #pragma unroll
            for (int mt = 0; mt < 4; ++mt) acc[mt] = (f32x4){bv,bv,bv,bv};
            for (int ks = 0; ks < 7; ++ks) {
                int k0 = ks*32 + lhi*8;
                short8b bh, bl;
                if (k0 + 8 <= 200) {
                    const float* wp = &W2[nc*200 + k0];
                    float4 w0 = *reinterpret_cast<const float4*>(wp);
                    float4 w1 = *reinterpret_cast<const float4*>(wp + 4);
                    split8(w0, w1, bh, bl);
                } else {
                    #pragma unroll
                    for (int i = 0; i < 8; ++i) { bh[i] = 0; bl[i] = 0; }
                }
                #pragma unroll
                for (int mt = 0; mt < 4; ++mt) {
                    int rr = mt*16 + l16;
                    short8b a = *reinterpret_cast<const short8b*>(
                        &h1s[rr*256 + ((((k0>>3) ^ (rr&7)))<<3)]);
                    acc[mt] = __builtin_amdgcn_mfma_f32_16x16x32_bf16(a, bh, acc[mt], 0,0,0);
                    acc[mt] = __builtin_amdgcn_mfma_f32_16x16x32_bf16(a, bl, acc[mt], 0,0,0);
                }
            }
            #pragma unroll
            for (int mt = 0; mt < 4; ++mt)
                #pragma unroll
                for (int q = 0; q < 4; ++q)
                    p[mt][q] = fmaf(w3v, felu(acc[mt][q]), p[mt][q]);
        }
        #pragma unroll
        for (int off = 1; off < 16; off <<= 1) {
            #pragma unroll
            for (int mt = 0; mt < 4; ++mt)
                #pragma unroll
                for (int q = 0; q < 4; ++q)
                    p[mt][q] += __shfl_xor(p[mt][q], off);
        }
        if (l16 == 0) {
            #pragma unroll
            for (int mt = 0; mt < 4; ++mt)
                #pragma unroll
                for (int q = 0; q < 4; ++q)
                    praw[wv][mt*16 + lhi*4 + q] = p[mt][q];
        }
        __syncthreads();
        if (tid < 64)
            rawv[brn][tid] = b3[0] + praw[0][tid] + praw[1][tid] + praw[2][tid] + praw[3][tid];
        __syncthreads();
    }

    if (tid < 64) {
        int row = row0 + tid;
        float T10 = 0.1f + 4.9f*fsigmoid(rawv[0][tid]);
        float M0  = 10000.0f*fsigmoid(rawv[1][tid]);
        Es[tid]  = __expf(-TR[row]/T10);
        M0s[tid] = M0;
        out[(size_t)B_TOT*T_LEN + row]         = T10;
        out[(size_t)B_TOT*T_LEN + B_TOT + row] = M0;
    }
    __syncthreads();
    for (int i = tid; i < 64*T_LEN; i += 256) {
        int rr = i / T_LEN, t = i - rr*T_LEN;
        int row = row0 + rr;
        float fa = FA[row*T_LEN + t];
        float s = __sinf(fa), c = __cosf(fa);
        float Ev = Es[rr];
        out[row*T_LEN + t] = (1.0f - Ev)*s*frcp(1.0f - c*Ev)*M0s[rr];
    }
}

extern "C" void kernel_launch(void* const* d_in, const int* in_sizes, int n_in,
                              void* d_out, int out_size, void* d_ws, size_t ws_size,
                              hipStream_t stream) {
    const float* Xin = (const float*)d_in[0];
    const float* FA  = (const float*)d_in[1];
    const float* TR  = (const float*)d_in[4];
    const float* Wih = (const float*)d_in[5];
    const float* Whh = (const float*)d_in[6];
    const float* bih = (const float*)d_in[7];
    const float* bhh = (const float*)d_in[8];
    const float* swT = (const float*)d_in[9];
    const float* swM = (const float*)d_in[10];
    const float* TW1 = (const float*)d_in[11]; const float* Tb1 = (const float*)d_in[12];
    const float* TW2 = (const float*)d_in[13]; const float* Tb2 = (const float*)d_in[14];
    const float* TW3 = (const float*)d_in[15]; const float* Tb3 = (const float*)d_in[16];
    const float* MW1 = (const float*)d_in[17]; const float* Mb1 = (const float*)d_in[18];
    const float* MW2 = (const float*)d_in[19]; const float* Mb2 = (const float*)d_in[20];
    const float* MW3 = (const float*)d_in[21]; const float* Mb3 = (const float*)d_in[22];
    float* out = (float*)d_out;

    float* hT = (float*)d_ws;
    float* hM = hT + (size_t)B_TOT*HD;

    gru_attn_mfma<<<B_TOT/64, 256, 0, stream>>>(Xin, FA, Wih, Whh, bih, bhh,
                                                swT, swM, hT, hM);
    mlp_mfma<<<B_TOT/64, 256, 0, stream>>>(hT, hM,
                                           TW1, Tb1, TW2, Tb2, TW3, Tb3,
                                           MW1, Mb1, MW2, Mb2, MW3, Mb3,
                                           FA, TR, out);
}

// Round 7
// 289.104 us; speedup vs baseline: 3.8392x; 1.0178x over previous
//
#include <hip/hip_runtime.h>

#define B_TOT 65536
#define T_LEN 34
#define HD 64
#define LOG2E 1.44269504088896340736f

typedef __attribute__((ext_vector_type(8))) short short8b;
typedef __attribute__((ext_vector_type(4))) short short4b;
typedef __attribute__((ext_vector_type(4))) float f32x4;
typedef __attribute__((ext_vector_type(4))) unsigned int u32x4;

__device__ __forceinline__ float frcp(float x){ return __builtin_amdgcn_rcpf(x); }
__device__ __forceinline__ float fexp2(float x){ return __builtin_amdgcn_exp2f(x); }
__device__ __forceinline__ float fsigmoid(float x){ return frcp(1.0f+__expf(-x)); }
__device__ __forceinline__ float felu(float x){ return x>0.0f ? x : (__expf(x)-1.0f); }

__device__ __forceinline__ unsigned short f2bf_rne(float f){
    unsigned int u = __float_as_uint(f);
    u += 0x7FFFu + ((u >> 16) & 1u);
    return (unsigned short)(u >> 16);
}
__device__ __forceinline__ float bf2f(unsigned short h){
    return __uint_as_float(((unsigned int)h) << 16);
}
__device__ __forceinline__ void split8(const float4& a, const float4& b,
                                       short8b& hi, short8b& lo){
    float f[8] = {a.x,a.y,a.z,a.w,b.x,b.y,b.z,b.w};
    #pragma unroll
    for (int i = 0; i < 8; ++i){
        unsigned short h = f2bf_rne(f[i]);
        hi[i] = (short)h;
        lo[i] = (short)f2bf_rne(f[i] - bf2f(h));
    }
}
__device__ __forceinline__ unsigned int cvt_pk_bf16(float lo, float hi){
    unsigned int r;
    asm("v_cvt_pk_bf16_f32 %0, %1, %2" : "=v"(r) : "v"(lo), "v"(hi));
    return r;
}
// swizzle constant for row r (applied at 16B granule within a 128B HL row)
__device__ __forceinline__ int hswz(int r){ return ((r ^ (r >> 3)) & 7); }

// ---------------- Kernel A: forward-fill + GRU (MFMA) + attention pooling ----------------
// 4 waves/block, 16 rows/wave. k-PERMUTED h layout: HL position p = l16*4 + g
// holds unit u(p) = (p&3)*16 + (p>>2)  ->  per-lane h writes are one b64.
// B-tiles (Whh, scaled -L / +2L), replicated score tiles (no shuffles), and
// zero-padded ext tiles ([x,fv,1] x [Wih|bias]) all live in LDS; acc C-init
// is a shared zero4 (bias comes in via the ext MFMA's k=2 row).
__global__ __launch_bounds__(256)
void gru_attn_mfma(const float* __restrict__ Xin, const float* __restrict__ FA,
                   const float* __restrict__ Wih, const float* __restrict__ Whh,
                   const float* __restrict__ bih, const float* __restrict__ bhh,
                   const float* __restrict__ swT, const float* __restrict__ swM,
                   float* __restrict__ hT_out, float* __restrict__ hM_out)
{
    __shared__ __align__(16) unsigned short WF[28*512];   // 28 KB: 24 gate + 4 score slots
    __shared__ __align__(16) unsigned short XW[12*512];   // 12 KB: ext tiles (rows k=0..2 nonzero)
    __shared__ __align__(16) unsigned short HL[4][1024];  // 8 KB : per-wave h (k-permuted, swizzled)
    __shared__ unsigned int XF[T_LEN*64];                 // 8.5 KB: [t][row] packed (x,fv) bf16x2

    const int tid  = threadIdx.x;
    const int lane = tid & 63;
    const int wv   = tid >> 6;
    const int l16  = lane & 15;
    const int lhi  = lane >> 4;

    // ---- stage gate + score B-fragments (k-permuted) ----
    for (int f = wv; f < 28; f += 4) {
        unsigned short* dst = &WF[f*512 + lane*8];
        if (f < 24) {
            int ks = f / 12, nt = f % 12;
            int u_out = nt*16 + l16;
            float scale = (nt < 8) ? -LOG2E : 2.0f*LOG2E;
            #pragma unroll
            for (int j = 0; j < 8; ++j) {
                int k = ks*32 + lhi*8 + j;
                int u_in = (k & 3)*16 + (k >> 2);          // k-perm
                dst[j] = f2bf_rne(scale*Whh[u_out*64 + u_in]);
            }
        } else {
            int s = f - 24;                                 // 0,1: swT halves; 2,3: swM
            const float* src = (s >= 2) ? swM : swT;
            int ks = s & 1;
            #pragma unroll
            for (int j = 0; j < 8; ++j) {
                int k = ks*32 + lhi*8 + j;
                int u_in = (k & 3)*16 + (k >> 2);
                dst[j] = f2bf_rne(LOG2E*src[u_in]);         // replicated across all 16 cols
            }
        }
    }
    // ---- ext tiles: zero-fill then write rows k=0..2 ----
    for (int i = tid; i < 12*512; i += 256) XW[i] = 0;
    __syncthreads();    // zero-fill visible before sparse writes (different threads)
    if (lhi == 0) {
        for (int nt = wv; nt < 12; nt += 4) {
            int u_abs = (nt < 8) ? (nt*16 + l16) : (128 + (nt-8)*16 + l16);
            float s = (nt < 8) ? -LOG2E : 2.0f*LOG2E;
            float bias = (nt < 8) ? -LOG2E*(bih[u_abs] + bhh[u_abs])
                                  : 2.0f*LOG2E*bih[u_abs];
            unsigned short* dst = &XW[nt*512 + lane*8];
            dst[0] = f2bf_rne(s*Wih[u_abs*2]);
            dst[1] = f2bf_rne(s*Wih[u_abs*2+1]);
            dst[2] = f2bf_rne(bias);
        }
    }

    #pragma unroll
    for (int i = 0; i < 16; ++i) HL[wv][i*64 + lane] = 0;

    const int rowbase = blockIdx.x*64 + wv*16;

    // ---- forward fill (segmented LOCF); lane = time ----
    for (int rr = 0; rr < 16; ++rr) {
        int row = rowbase + rr;
        float X = 0.0f, fa = 0.0f; int idx = -1;
        if (lane < T_LEN) {
            X  = Xin[row*T_LEN + lane];
            fa = FA [row*T_LEN + lane];
            if (X != 0.0f) idx = lane;
        }
        #pragma unroll
        for (int off = 1; off < 64; off <<= 1) {
            int v = __shfl_up(idx, off);
            if (lane >= off && v > idx) idx = v;
        }
        int gsrc = idx < 0 ? 0 : idx;
        float Xg = __shfl(X,  gsrc);
        float fg = __shfl(fa, gsrc);
        if (idx < 0) { Xg = 0.0f; fg = 0.0f; }
        if (lane < T_LEN)
            XF[lane*64 + wv*16 + rr] =
                (unsigned int)f2bf_rne(Xg) | ((unsigned int)f2bf_rne(fg) << 16);
    }

    // bhh_n (inside r*(.)) kept as per-lane regs, applied via fma
    float biasN[4];
    #pragma unroll
    for (int g = 0; g < 4; ++g) biasN[g] = 2.0f*LOG2E*bhh[128 + g*16 + l16];

    __syncthreads();

    // A-fragment addresses (row = l16), swizzled at 16B granule
    const int sA    = hswz(l16) << 3;                      // in shorts
    const int aoff0 = l16*64 + (( lhi   *8) ^ sA);
    const int aoff1 = l16*64 + (((4+lhi)*8) ^ sA);
    const int xfidx = wv*16 + l16;
    const unsigned int extk2 = (lhi == 0) ? 0x00003f80u : 0u;   // bf16(1.0) in k=2
    const f32x4 zero4 = (f32x4){0.f, 0.f, 0.f, 0.f};

    float2 hreg2[4][2];
    float2 numT2[4][2], numM2[4][2];
    float  denT[4] = {}, denM[4] = {};
    #pragma unroll
    for (int q = 0; q < 4; ++q)
        #pragma unroll
        for (int j = 0; j < 2; ++j) {
            hreg2[q][j] = make_float2(0.f, 0.f);
            numT2[q][j] = make_float2(0.f, 0.f);
            numM2[q][j] = make_float2(0.f, 0.f);
        }

    const unsigned short* HLr = HL[wv];
    unsigned short*       HLw = HL[wv];
    const unsigned short* WFl = &WF[lane*8];
    const unsigned short* XWl = &XW[lane*8];

    for (int t = 0; t < T_LEN; ++t) {
        short8b a0 = *reinterpret_cast<const short8b*>(&HLr[aoff0]);
        short8b a1 = *reinterpret_cast<const short8b*>(&HLr[aoff1]);
        unsigned int xw = XF[t*64 + xfidx];
        u32x4 aeu = { (lhi == 0) ? xw : 0u, extk2, 0u, 0u };
        short8b aext = __builtin_bit_cast(short8b, aeu);

        // score tiles (replicated cols): every lane gets its rows' scores locally
        f32x4 accT = __builtin_amdgcn_mfma_f32_16x16x32_bf16(
            a0, *reinterpret_cast<const short8b*>(WFl + 24*512), zero4, 0,0,0);
        accT = __builtin_amdgcn_mfma_f32_16x16x32_bf16(
            a1, *reinterpret_cast<const short8b*>(WFl + 25*512), accT, 0,0,0);
        f32x4 accM = __builtin_amdgcn_mfma_f32_16x16x32_bf16(
            a0, *reinterpret_cast<const short8b*>(WFl + 26*512), zero4, 0,0,0);
        accM = __builtin_amdgcn_mfma_f32_16x16x32_bf16(
            a1, *reinterpret_cast<const short8b*>(WFl + 27*512), accM, 0,0,0);

        if (t) {   // pool h_{t-1} (state entering this step); t=0 state is not an output
            #pragma unroll
            for (int q = 0; q < 4; ++q) {
                float eT = fexp2(accT[q]);
                float eM = fexp2(accM[q]);
                denT[q] += eT; denM[q] += eM;
                #pragma unroll
                for (int j = 0; j < 2; ++j) {
                    numT2[q][j].x = fmaf(eT, hreg2[q][j].x, numT2[q][j].x);
                    numT2[q][j].y = fmaf(eT, hreg2[q][j].y, numT2[q][j].y);
                    numM2[q][j].x = fmaf(eM, hreg2[q][j].x, numM2[q][j].x);
                    numM2[q][j].y = fmaf(eM, hreg2[q][j].y, numM2[q][j].y);
                }
            }
        }

        // gate trios per unit-group g; bias arrives via ext MFMA k=2 row
        #pragma unroll
        for (int g = 0; g < 4; ++g) {
            f32x4 ar = __builtin_amdgcn_mfma_f32_16x16x32_bf16(
                aext, *reinterpret_cast<const short8b*>(XWl + (g   )*512), zero4, 0,0,0);
            ar = __builtin_amdgcn_mfma_f32_16x16x32_bf16(
                a0, *reinterpret_cast<const short8b*>(WFl + (g   )*512), ar, 0,0,0);
            ar = __builtin_amdgcn_mfma_f32_16x16x32_bf16(
                a1, *reinterpret_cast<const short8b*>(WFl + (12+g)*512), ar, 0,0,0);
            f32x4 az = __builtin_amdgcn_mfma_f32_16x16x32_bf16(
                aext, *reinterpret_cast<const short8b*>(XWl + (4+g )*512), zero4, 0,0,0);
            az = __builtin_amdgcn_mfma_f32_16x16x32_bf16(
                a0, *reinterpret_cast<const short8b*>(WFl + (4+g )*512), az, 0,0,0);
            az = __builtin_amdgcn_mfma_f32_16x16x32_bf16(
                a1, *reinterpret_cast<const short8b*>(WFl + (16+g)*512), az, 0,0,0);
            f32x4 anx = __builtin_amdgcn_mfma_f32_16x16x32_bf16(
                aext, *reinterpret_cast<const short8b*>(XWl + (8+g )*512), zero4, 0,0,0);
            f32x4 anh = __builtin_amdgcn_mfma_f32_16x16x32_bf16(
                a0, *reinterpret_cast<const short8b*>(WFl + (8+g )*512), zero4, 0,0,0);
            anh = __builtin_amdgcn_mfma_f32_16x16x32_bf16(
                a1, *reinterpret_cast<const short8b*>(WFl + (20+g)*512), anh, 0,0,0);
            #pragma unroll
            for (int q = 0; q < 4; ++q) {
                float r  = frcp(1.0f + fexp2(ar[q]));
                float z  = frcp(1.0f + fexp2(az[q]));
                float v  = fmaf(r, anh[q], fmaf(r, biasN[g], anx[q]));
                float n  = fmaf(-2.0f, frcp(1.0f + fexp2(v)), 1.0f);
                float h  = (g & 1) ? hreg2[q][g>>1].y : hreg2[q][g>>1].x;
                float hn = fmaf(z, h - n, n);
                if (g & 1) hreg2[q][g>>1].y = hn; else hreg2[q][g>>1].x = hn;
            }
        }

        // packed h writeback: one b64 per q (k-permuted layout)
        #pragma unroll
        for (int q = 0; q < 4; ++q) {
            int rloc = lhi*4 + q;
            unsigned int d0 = cvt_pk_bf16(hreg2[q][0].x, hreg2[q][0].y);
            unsigned int d1 = cvt_pk_bf16(hreg2[q][1].x, hreg2[q][1].y);
            int so = rloc*64 + ((l16*4) ^ (hswz(rloc) << 3));
            *reinterpret_cast<uint2*>(&HLw[so]) = make_uint2(d0, d1);
        }
    }

    // ---- pool final state ----
    {
        short8b a0 = *reinterpret_cast<const short8b*>(&HLr[aoff0]);
        short8b a1 = *reinterpret_cast<const short8b*>(&HLr[aoff1]);
        f32x4 accT = __builtin_amdgcn_mfma_f32_16x16x32_bf16(
            a0, *reinterpret_cast<const short8b*>(WFl + 24*512), zero4, 0,0,0);
        accT = __builtin_amdgcn_mfma_f32_16x16x32_bf16(
            a1, *reinterpret_cast<const short8b*>(WFl + 25*512), accT, 0,0,0);
        f32x4 accM = __builtin_amdgcn_mfma_f32_16x16x32_bf16(
            a0, *reinterpret_cast<const short8b*>(WFl + 26*512), zero4, 0,0,0);
        accM = __builtin_amdgcn_mfma_f32_16x16x32_bf16(
            a1, *reinterpret_cast<const short8b*>(WFl + 27*512), accM, 0,0,0);
        #pragma unroll
        for (int q = 0; q < 4; ++q) {
            float eT = fexp2(accT[q]);
            float eM = fexp2(accM[q]);
            denT[q] += eT; denM[q] += eM;
            #pragma unroll
            for (int j = 0; j < 2; ++j) {
                numT2[q][j].x = fmaf(eT, hreg2[q][j].x, numT2[q][j].x);
                numT2[q][j].y = fmaf(eT, hreg2[q][j].y, numT2[q][j].y);
                numM2[q][j].x = fmaf(eM, hreg2[q][j].x, numM2[q][j].x);
                numM2[q][j].y = fmaf(eM, hreg2[q][j].y, numM2[q][j].y);
            }
        }
    }

    #pragma unroll
    for (int q = 0; q < 4; ++q) {
        int row = rowbase + lhi*4 + q;
        float rT = frcp(denT[q]), rM = frcp(denM[q]);
        #pragma unroll
        for (int j = 0; j < 2; ++j) {
            hT_out[row*HD + (2*j  )*16 + l16] = numT2[q][j].x*rT;
            hT_out[row*HD + (2*j+1)*16 + l16] = numT2[q][j].y*rT;
            hM_out[row*HD + (2*j  )*16 + l16] = numM2[q][j].x*rM;
            hM_out[row*HD + (2*j+1)*16 + l16] = numM2[q][j].y*rM;
        }
    }
}

// ---------------- Kernel B: MFMA MLP heads + T10/M0 + X_out (unchanged) ----------------
__global__ __launch_bounds__(256)
void mlp_mfma(const float* __restrict__ hT, const float* __restrict__ hM,
    const float* __restrict__ TW1, const float* __restrict__ Tb1,
    const float* __restrict__ TW2, const float* __restrict__ Tb2,
    const float* __restrict__ TW3, const float* __restrict__ Tb3,
    const float* __restrict__ MW1, const float* __restrict__ Mb1,
    const float* __restrict__ MW2, const float* __restrict__ Mb2,
    const float* __restrict__ MW3, const float* __restrict__ Mb3,
    const float* __restrict__ FA, const float* __restrict__ TR,
    float* __restrict__ out)
{
    __shared__ __align__(16) unsigned short xh[2*64*64];
    __shared__ __align__(16) unsigned short h1s[64*256];
    __shared__ float praw[4][64];
    __shared__ float rawv[2][64];
    __shared__ float Es[64], M0s[64];

    const int tid  = threadIdx.x;
    const int lane = tid & 63;
    const int wv   = tid >> 6;
    const int l16  = lane & 15;
    const int lhi  = lane >> 4;
    const int row0 = blockIdx.x*64;

    {
        int r  = tid >> 2;
        int k0 = (tid & 3) * 16;
        int rx = r & 7;
        const float* pT = &hT[(row0+r)*64 + k0];
        const float* pM = &hM[(row0+r)*64 + k0];
        #pragma unroll
        for (int j = 0; j < 4; ++j) {
            float4 vT = *reinterpret_cast<const float4*>(pT + 4*j);
            float4 vM = *reinterpret_cast<const float4*>(pM + 4*j);
            int kk = k0 + 4*j;
            int ad = r*64 + ((((kk>>3) ^ rx))<<3) + (kk&7);
            short4b sT = { (short)f2bf_rne(vT.x), (short)f2bf_rne(vT.y),
                           (short)f2bf_rne(vT.z), (short)f2bf_rne(vT.w) };
            short4b sM = { (short)f2bf_rne(vM.x), (short)f2bf_rne(vM.y),
                           (short)f2bf_rne(vM.z), (short)f2bf_rne(vM.w) };
            *reinterpret_cast<short4b*>(&xh[ad])        = sT;
            *reinterpret_cast<short4b*>(&xh[4096 + ad]) = sM;
        }
        for (int i = tid; i < 64*24; i += 256) {
            int rr = i / 24, kk = 200 + i % 24;
            h1s[rr*256 + ((((kk>>3) ^ (rr&7)))<<3) + (kk&7)] = 0;
        }
    }
    __syncthreads();

    for (int brn = 0; brn < 2; ++brn) {
        const float* W1 = brn ? MW1 : TW1; const float* b1 = brn ? Mb1 : Tb1;
        const float* W2 = brn ? MW2 : TW2; const float* b2 = brn ? Mb2 : Tb2;
        const float* W3 = brn ? MW3 : TW3; const float* b3 = brn ? Mb3 : Tb3;

        for (int s = 0; s < 4; ++s) {
            int nt = wv + 4*s;
            if (nt > 12) break;
            int n  = nt*16 + l16;
            int nc = n < 200 ? n : 199;
            float bv = b1[nc];
            f32x4 acc[4];
            #pragma unroll
            for (int mt = 0; mt < 4; ++mt) acc[mt] = (f32x4){bv,bv,bv,bv};
            #pragma unroll
            for (int ks = 0; ks < 2; ++ks) {
                int k0 = ks*32 + lhi*8;
                const float* wp = &W1[nc*64 + k0];
                float4 w0 = *reinterpret_cast<const float4*>(wp);
                float4 w1 = *reinterpret_cast<const float4*>(wp + 4);
                short8b bh, bl;
                split8(w0, w1, bh, bl);
                #pragma unroll
                for (int mt = 0; mt < 4; ++mt) {
                    int rr = mt*16 + l16;
                    short8b a = *reinterpret_cast<const short8b*>(
                        &xh[brn*4096 + rr*64 + ((((k0>>3) ^ (rr&7)))<<3)]);
                    acc[mt] = __builtin_amdgcn_mfma_f32_16x16x32_bf16(a, bh, acc[mt], 0,0,0);
                    acc[mt] = __builtin_amdgcn_mfma_f32_16x16x32_bf16(a, bl, acc[mt], 0,0,0);
                }
            }
            if (n < 200) {
                #pragma unroll
                for (int mt = 0; mt < 4; ++mt) {
                    #pragma unroll
                    for (int q = 0; q < 4; ++q) {
                        int rr = mt*16 + lhi*4 + q;
                        h1s[rr*256 + ((((n>>3) ^ (rr&7)))<<3) + (n&7)] =
                            f2bf_rne(felu(acc[mt][q]));
                    }
                }
            }
        }
        __syncthreads();

        float p[4][4] = {};
        for (int s = 0; s < 4; ++s) {
            int nt = wv + 4*s;
            if (nt > 12) break;
            int n  = nt*16 + l16;
            int nc = n < 200 ? n : 199;
            float w3v = (n < 200) ? W3[nc] : 0.0f;
            float bv = b2[nc];
            f32x4 acc[4];
            #pragma unroll
            for (int mt = 0; mt < 4; ++mt) acc[mt] = (f32x4){bv,bv,bv,bv};
            for (int ks = 0; ks < 7; ++ks) {
                int k0 = ks*32 + lhi*8;
                short8b bh, bl;
                if (k0 + 8 <= 200) {
                    const float* wp = &W2[nc*200 + k0];
                    float4 w0 = *reinterpret_cast<const float4*>(wp);
                    float4 w1 = *reinterpret_cast<const float4*>(wp + 4);
                    split8(w0, w1, bh, bl);
                } else {
                    #pragma unroll
                    for (int i = 0; i < 8; ++i) { bh[i] = 0; bl[i] = 0; }
                }
                #pragma unroll
                for (int mt = 0; mt < 4; ++mt) {
                    int rr = mt*16 + l16;
                    short8b a = *reinterpret_cast<const short8b*>(
                        &h1s[rr*256 + ((((k0>>3) ^ (rr&7)))<<3)]);
                    acc[mt] = __builtin_amdgcn_mfma_f32_16x16x32_bf16(a, bh, acc[mt], 0,0,0);
                    acc[mt] = __builtin_amdgcn_mfma_f32_16x16x32_bf16(a, bl, acc[mt], 0,0,0);
                }
            }
            #pragma unroll
            for (int mt = 0; mt < 4; ++mt)
                #pragma unroll
                for (int q = 0; q < 4; ++q)
                    p[mt][q] = fmaf(w3v, felu(acc[mt][q]), p[mt][q]);
        }
        #pragma unroll
        for (int off = 1; off < 16; off <<= 1) {
            #pragma unroll
            for (int mt = 0; mt < 4; ++mt)
                #pragma unroll
                for (int q = 0; q < 4; ++q)
                    p[mt][q] += __shfl_xor(p[mt][q], off);
        }
        if (l16 == 0) {
            #pragma unroll
            for (int mt = 0; mt < 4; ++mt)
                #pragma unroll
                for (int q = 0; q < 4; ++q)
                    praw[wv][mt*16 + lhi*4 + q] = p[mt][q];
        }
        __syncthreads();
        if (tid < 64)
            rawv[brn][tid] = b3[0] + praw[0][tid] + praw[1][tid] + praw[2][tid] + praw[3][tid];
        __syncthreads();
    }

    if (tid < 64) {
        int row = row0 + tid;
        float T10 = 0.1f + 4.9f*fsigmoid(rawv[0][tid]);
        float M0  = 10000.0f*fsigmoid(rawv[1][tid]);
        Es[tid]  = __expf(-TR[row]/T10);
        M0s[tid] = M0;
        out[(size_t)B_TOT*T_LEN + row]         = T10;
        out[(size_t)B_TOT*T_LEN + B_TOT + row] = M0;
    }
    __syncthreads();
    for (int i = tid; i < 64*T_LEN; i += 256) {
        int rr = i / T_LEN, t = i - rr*T_LEN;
        int row = row0 + rr;
        float fa = FA[row*T_LEN + t];
        float s = __sinf(fa), c = __cosf(fa);
        float Ev = Es[rr];
        out[row*T_LEN + t] = (1.0f - Ev)*s*frcp(1.0f - c*Ev)*M0s[rr];
    }
}

extern "C" void kernel_launch(void* const* d_in, const int* in_sizes, int n_in,
                              void* d_out, int out_size, void* d_ws, size_t ws_size,
                              hipStream_t stream) {
    const float* Xin = (const float*)d_in[0];
    const float* FA  = (const float*)d_in[1];
    const float* TR  = (const float*)d_in[4];
    const float* Wih = (const float*)d_in[5];
    const float* Whh = (const float*)d_in[6];
    const float* bih = (const float*)d_in[7];
    const float* bhh = (const float*)d_in[8];
    const float* swT = (const float*)d_in[9];
    const float* swM = (const float*)d_in[10];
    const float* TW1 = (const float*)d_in[11]; const float* Tb1 = (const float*)d_in[12];
    const float* TW2 = (const float*)d_in[13]; const float* Tb2 = (const float*)d_in[14];
    const float* TW3 = (const float*)d_in[15]; const float* Tb3 = (const float*)d_in[16];
    const float* MW1 = (const float*)d_in[17]; const float* Mb1 = (const float*)d_in[18];
    const float* MW2 = (const float*)d_in[19]; const float* Mb2 = (const float*)d_in[20];
    const float* MW3 = (const float*)d_in[21]; const float* Mb3 = (const float*)d_in[22];
    float* out = (float*)d_out;

    float* hT = (float*)d_ws;
    float* hM = hT + (size_t)B_TOT*HD;

    gru_attn_mfma<<<B_TOT/64, 256, 0, stream>>>(Xin, FA, Wih, Whh, bih, bhh,
                                                swT, swM, hT, hM);
    mlp_mfma<<<B_TOT/64, 256, 0, stream>>>(hT, hM,
                                           TW1, Tb1, TW2, Tb2, TW3, Tb3,
                                           MW1, Mb1, MW2, Mb2, MW3, Mb3,
                                           FA, TR, out);
}

// Round 8
// 282.974 us; speedup vs baseline: 3.9224x; 1.0217x over previous
//
#include <hip/hip_runtime.h>

#define B_TOT 65536
#define T_LEN 34
#define HD 64
#define LOG2E 1.44269504088896340736f

typedef __attribute__((ext_vector_type(8))) short short8b;
typedef __attribute__((ext_vector_type(4))) short short4b;
typedef __attribute__((ext_vector_type(4))) float f32x4;
typedef __attribute__((ext_vector_type(4))) unsigned int u32x4;

__device__ __forceinline__ float frcp(float x){ return __builtin_amdgcn_rcpf(x); }
__device__ __forceinline__ float fexp2(float x){ return __builtin_amdgcn_exp2f(x); }
__device__ __forceinline__ float fsigmoid(float x){ return frcp(1.0f+__expf(-x)); }
__device__ __forceinline__ float felu(float x){ return x>0.0f ? x : (__expf(x)-1.0f); }

__device__ __forceinline__ unsigned short f2bf_rne(float f){
    unsigned int u = __float_as_uint(f);
    u += 0x7FFFu + ((u >> 16) & 1u);
    return (unsigned short)(u >> 16);
}
__device__ __forceinline__ float bf2f(unsigned short h){
    return __uint_as_float(((unsigned int)h) << 16);
}
__device__ __forceinline__ void split8(const float4& a, const float4& b,
                                       short8b& hi, short8b& lo){
    float f[8] = {a.x,a.y,a.z,a.w,b.x,b.y,b.z,b.w};
    #pragma unroll
    for (int i = 0; i < 8; ++i){
        unsigned short h = f2bf_rne(f[i]);
        hi[i] = (short)h;
        lo[i] = (short)f2bf_rne(f[i] - bf2f(h));
    }
}
__device__ __forceinline__ unsigned int cvt_pk_bf16(float lo, float hi){
    unsigned int r;
    asm("v_cvt_pk_bf16_f32 %0, %1, %2" : "=v"(r) : "v"(lo), "v"(hi));
    return r;
}
// swizzle constant for row r (applied at 16B granule within a 128B HL row)
__device__ __forceinline__ int hswz(int r){ return ((r ^ (r >> 3)) & 7); }

// ---------------- Kernel A: forward-fill + GRU (MFMA) + attention pooling ----------------
// 4 waves/block, 16 rows/wave. k-PERMUTED h layout (unit u(p)=(p&3)*16+(p>>2))
// -> per-lane h writes are one b64. Ext tiles ([x,fv,1] x [Wih|bias]) stored
// COMPACT (rows k=0..2 only, [12][16][4] shorts = 1.5 KB) and reconstructed
// per-lane as {b64,0,0}. LDS total 46 KB -> 3 blocks/CU (was 57.9 KB -> 2).
__global__ __launch_bounds__(256)
void gru_attn_mfma(const float* __restrict__ Xin, const float* __restrict__ FA,
                   const float* __restrict__ Wih, const float* __restrict__ Whh,
                   const float* __restrict__ bih, const float* __restrict__ bhh,
                   const float* __restrict__ swT, const float* __restrict__ swM,
                   float* __restrict__ hT_out, float* __restrict__ hM_out)
{
    __shared__ __align__(16) unsigned short WF[28*512];    // 28 KB: 24 gate + 4 score tiles
    __shared__ __align__(16) unsigned short HL[4][1024];   // 8 KB : per-wave h (k-permuted)
    __shared__ unsigned int XF[T_LEN*64];                  // 8.5 KB: [t][row] packed (x,fv)
    __shared__ __align__(8)  unsigned short XWc[12][16][4];// 1.5 KB: compact ext rows k=0..2

    const int tid  = threadIdx.x;
    const int lane = tid & 63;
    const int wv   = tid >> 6;
    const int l16  = lane & 15;
    const int lhi  = lane >> 4;

    // ---- stage gate + score B-fragments (k-permuted) ----
    for (int f = wv; f < 28; f += 4) {
        unsigned short* dst = &WF[f*512 + lane*8];
        if (f < 24) {
            int ks = f / 12, nt = f % 12;
            int u_out = nt*16 + l16;
            float scale = (nt < 8) ? -LOG2E : 2.0f*LOG2E;
            #pragma unroll
            for (int j = 0; j < 8; ++j) {
                int k = ks*32 + lhi*8 + j;
                int u_in = (k & 3)*16 + (k >> 2);          // k-perm
                dst[j] = f2bf_rne(scale*Whh[u_out*64 + u_in]);
            }
        } else {
            int s = f - 24;                                 // 0,1: swT halves; 2,3: swM
            const float* src = (s >= 2) ? swM : swT;
            int ks = s & 1;
            #pragma unroll
            for (int j = 0; j < 8; ++j) {
                int k = ks*32 + lhi*8 + j;
                int u_in = (k & 3)*16 + (k >> 2);
                dst[j] = f2bf_rne(LOG2E*src[u_in]);         // replicated across all 16 cols
            }
        }
    }
    // ---- compact ext tiles: [nt][u16] -> (s*Wih0, s*Wih1, bias, 0) ----
    if (tid < 192) {
        int nt  = tid >> 4;
        int u16 = tid & 15;
        int u_abs = (nt < 8) ? (nt*16 + u16) : (128 + (nt-8)*16 + u16);
        float s = (nt < 8) ? -LOG2E : 2.0f*LOG2E;
        float bias = (nt < 8) ? -LOG2E*(bih[u_abs] + bhh[u_abs])
                              : 2.0f*LOG2E*bih[u_abs];
        XWc[nt][u16][0] = f2bf_rne(s*Wih[u_abs*2]);
        XWc[nt][u16][1] = f2bf_rne(s*Wih[u_abs*2+1]);
        XWc[nt][u16][2] = f2bf_rne(bias);
        XWc[nt][u16][3] = 0;
    }

    #pragma unroll
    for (int i = 0; i < 16; ++i) HL[wv][i*64 + lane] = 0;

    const int rowbase = blockIdx.x*64 + wv*16;

    // ---- forward fill (segmented LOCF); lane = time ----
    for (int rr = 0; rr < 16; ++rr) {
        int row = rowbase + rr;
        float X = 0.0f, fa = 0.0f; int idx = -1;
        if (lane < T_LEN) {
            X  = Xin[row*T_LEN + lane];
            fa = FA [row*T_LEN + lane];
            if (X != 0.0f) idx = lane;
        }
        #pragma unroll
        for (int off = 1; off < 64; off <<= 1) {
            int v = __shfl_up(idx, off);
            if (lane >= off && v > idx) idx = v;
        }
        int gsrc = idx < 0 ? 0 : idx;
        float Xg = __shfl(X,  gsrc);
        float fg = __shfl(fa, gsrc);
        if (idx < 0) { Xg = 0.0f; fg = 0.0f; }
        if (lane < T_LEN)
            XF[lane*64 + wv*16 + rr] =
                (unsigned int)f2bf_rne(Xg) | ((unsigned int)f2bf_rne(fg) << 16);
    }

    // bhh_n (inside r*(.)) kept as per-lane regs, applied via fma
    float biasN[4];
    #pragma unroll
    for (int g = 0; g < 4; ++g) biasN[g] = 2.0f*LOG2E*bhh[128 + g*16 + l16];

    __syncthreads();

    // A-fragment addresses (row = l16), swizzled at 16B granule
    const int sA    = hswz(l16) << 3;                      // in shorts
    const int aoff0 = l16*64 + (( lhi   *8) ^ sA);
    const int aoff1 = l16*64 + (((4+lhi)*8) ^ sA);
    const int xfidx = wv*16 + l16;
    const unsigned int extk2 = (lhi == 0) ? 0x00003f80u : 0u;   // bf16(1.0) in k=2
    const bool ext0 = (lhi == 0);
    const f32x4 zero4 = (f32x4){0.f, 0.f, 0.f, 0.f};

    float2 hreg2[4][2];
    float2 numT2[4][2], numM2[4][2];
    float  denT[4] = {}, denM[4] = {};
    #pragma unroll
    for (int q = 0; q < 4; ++q)
        #pragma unroll
        for (int j = 0; j < 2; ++j) {
            hreg2[q][j] = make_float2(0.f, 0.f);
            numT2[q][j] = make_float2(0.f, 0.f);
            numM2[q][j] = make_float2(0.f, 0.f);
        }

    const unsigned short* HLr = HL[wv];
    unsigned short*       HLw = HL[wv];
    const unsigned short* WFl = &WF[lane*8];
    const uint2*          XWp = reinterpret_cast<const uint2*>(&XWc[0][0][0]);

    for (int t = 0; t < T_LEN; ++t) {
        short8b a0 = *reinterpret_cast<const short8b*>(&HLr[aoff0]);
        short8b a1 = *reinterpret_cast<const short8b*>(&HLr[aoff1]);
        unsigned int xw = XF[t*64 + xfidx];
        u32x4 aeu = { ext0 ? xw : 0u, extk2, 0u, 0u };
        short8b aext = __builtin_bit_cast(short8b, aeu);

        // score tiles (replicated cols): every lane gets its rows' scores locally
        f32x4 accT = __builtin_amdgcn_mfma_f32_16x16x32_bf16(
            a0, *reinterpret_cast<const short8b*>(WFl + 24*512), zero4, 0,0,0);
        accT = __builtin_amdgcn_mfma_f32_16x16x32_bf16(
            a1, *reinterpret_cast<const short8b*>(WFl + 25*512), accT, 0,0,0);
        f32x4 accM = __builtin_amdgcn_mfma_f32_16x16x32_bf16(
            a0, *reinterpret_cast<const short8b*>(WFl + 26*512), zero4, 0,0,0);
        accM = __builtin_amdgcn_mfma_f32_16x16x32_bf16(
            a1, *reinterpret_cast<const short8b*>(WFl + 27*512), accM, 0,0,0);

        if (t) {   // pool h_{t-1} (state entering this step); t=0 state is not an output
            #pragma unroll
            for (int q = 0; q < 4; ++q) {
                float eT = fexp2(accT[q]);
                float eM = fexp2(accM[q]);
                denT[q] += eT; denM[q] += eM;
                #pragma unroll
                for (int j = 0; j < 2; ++j) {
                    numT2[q][j].x = fmaf(eT, hreg2[q][j].x, numT2[q][j].x);
                    numT2[q][j].y = fmaf(eT, hreg2[q][j].y, numT2[q][j].y);
                    numM2[q][j].x = fmaf(eM, hreg2[q][j].x, numM2[q][j].x);
                    numM2[q][j].y = fmaf(eM, hreg2[q][j].y, numM2[q][j].y);
                }
            }
        }

        // gate trios per unit-group g; [Wih|bias] arrives via compact ext MFMA
        #pragma unroll
        for (int g = 0; g < 4; ++g) {
            uint2 er = XWp[(g   )*16 + l16];
            uint2 ez = XWp[(4+g )*16 + l16];
            uint2 en = XWp[(8+g )*16 + l16];
            u32x4 bru = { ext0 ? er.x : 0u, ext0 ? er.y : 0u, 0u, 0u };
            u32x4 bzu = { ext0 ? ez.x : 0u, ext0 ? ez.y : 0u, 0u, 0u };
            u32x4 bnu = { ext0 ? en.x : 0u, ext0 ? en.y : 0u, 0u, 0u };

            f32x4 ar = __builtin_amdgcn_mfma_f32_16x16x32_bf16(
                aext, __builtin_bit_cast(short8b, bru), zero4, 0,0,0);
            ar = __builtin_amdgcn_mfma_f32_16x16x32_bf16(
                a0, *reinterpret_cast<const short8b*>(WFl + (g   )*512), ar, 0,0,0);
            ar = __builtin_amdgcn_mfma_f32_16x16x32_bf16(
                a1, *reinterpret_cast<const short8b*>(WFl + (12+g)*512), ar, 0,0,0);
            f32x4 az = __builtin_amdgcn_mfma_f32_16x16x32_bf16(
                aext, __builtin_bit_cast(short8b, bzu), zero4, 0,0,0);
            az = __builtin_amdgcn_mfma_f32_16x16x32_bf16(
                a0, *reinterpret_cast<const short8b*>(WFl + (4+g )*512), az, 0,0,0);
            az = __builtin_amdgcn_mfma_f32_16x16x32_bf16(
                a1, *reinterpret_cast<const short8b*>(WFl + (16+g)*512), az, 0,0,0);
            f32x4 anx = __builtin_amdgcn_mfma_f32_16x16x32_bf16(
                aext, __builtin_bit_cast(short8b, bnu), zero4, 0,0,0);
            f32x4 anh = __builtin_amdgcn_mfma_f32_16x16x32_bf16(
                a0, *reinterpret_cast<const short8b*>(WFl + (8+g )*512), zero4, 0,0,0);
            anh = __builtin_amdgcn_mfma_f32_16x16x32_bf16(
                a1, *reinterpret_cast<const short8b*>(WFl + (20+g)*512), anh, 0,0,0);
            #pragma unroll
            for (int q = 0; q < 4; ++q) {
                float r  = frcp(1.0f + fexp2(ar[q]));
                float z  = frcp(1.0f + fexp2(az[q]));
                float v  = fmaf(r, anh[q], fmaf(r, biasN[g], anx[q]));
                float n  = fmaf(-2.0f, frcp(1.0f + fexp2(v)), 1.0f);
                float h  = (g & 1) ? hreg2[q][g>>1].y : hreg2[q][g>>1].x;
                float hn = fmaf(z, h - n, n);
                if (g & 1) hreg2[q][g>>1].y = hn; else hreg2[q][g>>1].x = hn;
            }
        }

        // packed h writeback: one b64 per q (k-permuted layout)
        #pragma unroll
        for (int q = 0; q < 4; ++q) {
            int rloc = lhi*4 + q;
            unsigned int d0 = cvt_pk_bf16(hreg2[q][0].x, hreg2[q][0].y);
            unsigned int d1 = cvt_pk_bf16(hreg2[q][1].x, hreg2[q][1].y);
            int so = rloc*64 + ((l16*4) ^ (hswz(rloc) << 3));
            *reinterpret_cast<uint2*>(&HLw[so]) = make_uint2(d0, d1);
        }
    }

    // ---- pool final state ----
    {
        short8b a0 = *reinterpret_cast<const short8b*>(&HLr[aoff0]);
        short8b a1 = *reinterpret_cast<const short8b*>(&HLr[aoff1]);
        f32x4 accT = __builtin_amdgcn_mfma_f32_16x16x32_bf16(
            a0, *reinterpret_cast<const short8b*>(WFl + 24*512), zero4, 0,0,0);
        accT = __builtin_amdgcn_mfma_f32_16x16x32_bf16(
            a1, *reinterpret_cast<const short8b*>(WFl + 25*512), accT, 0,0,0);
        f32x4 accM = __builtin_amdgcn_mfma_f32_16x16x32_bf16(
            a0, *reinterpret_cast<const short8b*>(WFl + 26*512), zero4, 0,0,0);
        accM = __builtin_amdgcn_mfma_f32_16x16x32_bf16(
            a1, *reinterpret_cast<const short8b*>(WFl + 27*512), accM, 0,0,0);
        #pragma unroll
        for (int q = 0; q < 4; ++q) {
            float eT = fexp2(accT[q]);
            float eM = fexp2(accM[q]);
            denT[q] += eT; denM[q] += eM;
            #pragma unroll
            for (int j = 0; j < 2; ++j) {
                numT2[q][j].x = fmaf(eT, hreg2[q][j].x, numT2[q][j].x);
                numT2[q][j].y = fmaf(eT, hreg2[q][j].y, numT2[q][j].y);
                numM2[q][j].x = fmaf(eM, hreg2[q][j].x, numM2[q][j].x);
                numM2[q][j].y = fmaf(eM, hreg2[q][j].y, numM2[q][j].y);
            }
        }
    }

    #pragma unroll
    for (int q = 0; q < 4; ++q) {
        int row = rowbase + lhi*4 + q;
        float rT = frcp(denT[q]), rM = frcp(denM[q]);
        #pragma unroll
        for (int j = 0; j < 2; ++j) {
            hT_out[row*HD + (2*j  )*16 + l16] = numT2[q][j].x*rT;
            hT_out[row*HD + (2*j+1)*16 + l16] = numT2[q][j].y*rT;
            hM_out[row*HD + (2*j  )*16 + l16] = numM2[q][j].x*rM;
            hM_out[row*HD + (2*j+1)*16 + l16] = numM2[q][j].y*rM;
        }
    }
}

// ---------------- Kernel B: MFMA MLP heads + T10/M0 + X_out (unchanged) ----------------
__global__ __launch_bounds__(256)
void mlp_mfma(const float* __restrict__ hT, const float* __restrict__ hM,
    const float* __restrict__ TW1, const float* __restrict__ Tb1,
    const float* __restrict__ TW2, const float* __restrict__ Tb2,
    const float* __restrict__ TW3, const float* __restrict__ Tb3,
    const float* __restrict__ MW1, const float* __restrict__ Mb1,
    const float* __restrict__ MW2, const float* __restrict__ Mb2,
    const float* __restrict__ MW3, const float* __restrict__ Mb3,
    const float* __restrict__ FA, const float* __restrict__ TR,
    float* __restrict__ out)
{
    __shared__ __align__(16) unsigned short xh[2*64*64];
    __shared__ __align__(16) unsigned short h1s[64*256];
    __shared__ float praw[4][64];
    __shared__ float rawv[2][64];
    __shared__ float Es[64], M0s[64];

    const int tid  = threadIdx.x;
    const int lane = tid & 63;
    const int wv   = tid >> 6;
    const int l16  = lane & 15;
    const int lhi  = lane >> 4;
    const int row0 = blockIdx.x*64;

    {
        int r  = tid >> 2;
        int k0 = (tid & 3) * 16;
        int rx = r & 7;
        const float* pT = &hT[(row0+r)*64 + k0];
        const float* pM = &hM[(row0+r)*64 + k0];
        #pragma unroll
        for (int j = 0; j < 4; ++j) {
            float4 vT = *reinterpret_cast<const float4*>(pT + 4*j);
            float4 vM = *reinterpret_cast<const float4*>(pM + 4*j);
            int kk = k0 + 4*j;
            int ad = r*64 + ((((kk>>3) ^ rx))<<3) + (kk&7);
            short4b sT = { (short)f2bf_rne(vT.x), (short)f2bf_rne(vT.y),
                           (short)f2bf_rne(vT.z), (short)f2bf_rne(vT.w) };
            short4b sM = { (short)f2bf_rne(vM.x), (short)f2bf_rne(vM.y),
                           (short)f2bf_rne(vM.z), (short)f2bf_rne(vM.w) };
            *reinterpret_cast<short4b*>(&xh[ad])        = sT;
            *reinterpret_cast<short4b*>(&xh[4096 + ad]) = sM;
        }
        for (int i = tid; i < 64*24; i += 256) {
            int rr = i / 24, kk = 200 + i % 24;
            h1s[rr*256 + ((((kk>>3) ^ (rr&7)))<<3) + (kk&7)] = 0;
        }
    }
    __syncthreads();

    for (int brn = 0; brn < 2; ++brn) {
        const float* W1 = brn ? MW1 : TW1; const float* b1 = brn ? Mb1 : Tb1;
        const float* W2 = brn ? MW2 : TW2; const float* b2 = brn ? Mb2 : Tb2;
        const float* W3 = brn ? MW3 : TW3; const float* b3 = brn ? Mb3 : Tb3;

        for (int s = 0; s < 4; ++s) {
            int nt = wv + 4*s;
            if (nt > 12) break;
            int n  = nt*16 + l16;
            int nc = n < 200 ? n : 199;
            float bv = b1[nc];
            f32x4 acc[4];
            #pragma unroll
            for (int mt = 0; mt < 4; ++mt) acc[mt] = (f32x4){bv,bv,bv,bv};
            #pragma unroll
            for (int ks = 0; ks < 2; ++ks) {
                int k0 = ks*32 + lhi*8;
                const float* wp = &W1[nc*64 + k0];
                float4 w0 = *reinterpret_cast<const float4*>(wp);
                float4 w1 = *reinterpret_cast<const float4*>(wp + 4);
                short8b bh, bl;
                split8(w0, w1, bh, bl);
                #pragma unroll
                for (int mt = 0; mt < 4; ++mt) {
                    int rr = mt*16 + l16;
                    short8b a = *reinterpret_cast<const short8b*>(
                        &xh[brn*4096 + rr*64 + ((((k0>>3) ^ (rr&7)))<<3)]);
                    acc[mt] = __builtin_amdgcn_mfma_f32_16x16x32_bf16(a, bh, acc[mt], 0,0,0);
                    acc[mt] = __builtin_amdgcn_mfma_f32_16x16x32_bf16(a, bl, acc[mt], 0,0,0);
                }
            }
            if (n < 200) {
                #pragma unroll
                for (int mt = 0; mt < 4; ++mt) {
                    #pragma unroll
                    for (int q = 0; q < 4; ++q) {
                        int rr = mt*16 + lhi*4 + q;
                        h1s[rr*256 + ((((n>>3) ^ (rr&7)))<<3) + (n&7)] =
                            f2bf_rne(felu(acc[mt][q]));
                    }
                }
            }
        }
        __syncthreads();

        float p[4][4] = {};
        for (int s = 0; s < 4; ++s) {
            int nt = wv + 4*s;
            if (nt > 12) break;
            int n  = nt*16 + l16;
            int nc = n < 200 ? n : 199;
            float w3v = (n < 200) ? W3[nc] : 0.0f;
            float bv = b2[nc];
            f32x4 acc[4];
            #pragma unroll
            for (int mt = 0; mt < 4; ++mt) acc[mt] = (f32x4){bv,bv,bv,bv};
            for (int ks = 0; ks < 7; ++ks) {
                int k0 = ks*32 + lhi*8;
                short8b bh, bl;
                if (k0 + 8 <= 200) {
                    const float* wp = &W2[nc*200 + k0];
                    float4 w0 = *reinterpret_cast<const float4*>(wp);
                    float4 w1 = *reinterpret_cast<const float4*>(wp + 4);
                    split8(w0, w1, bh, bl);
                } else {
                    #pragma unroll
                    for (int i = 0; i < 8; ++i) { bh[i] = 0; bl[i] = 0; }
                }
                #pragma unroll
                for (int mt = 0; mt < 4; ++mt) {
                    int rr = mt*16 + l16;
                    short8b a = *reinterpret_cast<const short8b*>(
                        &h1s[rr*256 + ((((k0>>3) ^ (rr&7)))<<3)]);
                    acc[mt] = __builtin_amdgcn_mfma_f32_16x16x32_bf16(a, bh, acc[mt], 0,0,0);
                    acc[mt] = __builtin_amdgcn_mfma_f32_16x16x32_bf16(a, bl, acc[mt], 0,0,0);
                }
            }
            #pragma unroll
            for (int mt = 0; mt < 4; ++mt)
                #pragma unroll
                for (int q = 0; q < 4; ++q)
                    p[mt][q] = fmaf(w3v, felu(acc[mt][q]), p[mt][q]);
        }
        #pragma unroll
        for (int off = 1; off < 16; off <<= 1) {
            #pragma unroll
            for (int mt = 0; mt < 4; ++mt)
                #pragma unroll
                for (int q = 0; q < 4; ++q)
                    p[mt][q] += __shfl_xor(p[mt][q], off);
        }
        if (l16 == 0) {
            #pragma unroll
            for (int mt = 0; mt < 4; ++mt)
                #pragma unroll
                for (int q = 0; q < 4; ++q)
                    praw[wv][mt*16 + lhi*4 + q] = p[mt][q];
        }
        __syncthreads();
        if (tid < 64)
            rawv[brn][tid] = b3[0] + praw[0][tid] + praw[1][tid] + praw[2][tid] + praw[3][tid];
        __syncthreads();
    }

    if (tid < 64) {
        int row = row0 + tid;
        float T10 = 0.1f + 4.9f*fsigmoid(rawv[0][tid]);
        float M0  = 10000.0f*fsigmoid(rawv[1][tid]);
        Es[tid]  = __expf(-TR[row]/T10);
        M0s[tid] = M0;
        out[(size_t)B_TOT*T_LEN + row]         = T10;
        out[(size_t)B_TOT*T_LEN + B_TOT + row] = M0;
    }
    __syncthreads();
    for (int i = tid; i < 64*T_LEN; i += 256) {
        int rr = i / T_LEN, t = i - rr*T_LEN;
        int row = row0 + rr;
        float fa = FA[row*T_LEN + t];
        float s = __sinf(fa), c = __cosf(fa);
        float Ev = Es[rr];
        out[row*T_LEN + t] = (1.0f - Ev)*s*frcp(1.0f - c*Ev)*M0s[rr];
    }
}

extern "C" void kernel_launch(void* const* d_in, const int* in_sizes, int n_in,
                              void* d_out, int out_size, void* d_ws, size_t ws_size,
                              hipStream_t stream) {
    const float* Xin = (const float*)d_in[0];
    const float* FA  = (const float*)d_in[1];
    const float* TR  = (const float*)d_in[4];
    const float* Wih = (const float*)d_in[5];
    const float* Whh = (const float*)d_in[6];
    const float* bih = (const float*)d_in[7];
    const float* bhh = (const float*)d_in[8];
    const float* swT = (const float*)d_in[9];
    const float* swM = (const float*)d_in[10];
    const float* TW1 = (const float*)d_in[11]; const float* Tb1 = (const float*)d_in[12];
    const float* TW2 = (const float*)d_in[13]; const float* Tb2 = (const float*)d_in[14];
    const float* TW3 = (const float*)d_in[15]; const float* Tb3 = (const float*)d_in[16];
    const float* MW1 = (const float*)d_in[17]; const float* Mb1 = (const float*)d_in[18];
    const float* MW2 = (const float*)d_in[19]; const float* Mb2 = (const float*)d_in[20];
    const float* MW3 = (const float*)d_in[21]; const float* Mb3 = (const float*)d_in[22];
    float* out = (float*)d_out;

    float* hT = (float*)d_ws;
    float* hM = hT + (size_t)B_TOT*HD;

    gru_attn_mfma<<<B_TOT/64, 256, 0, stream>>>(Xin, FA, Wih, Whh, bih, bhh,
                                                swT, swM, hT, hM);
    mlp_mfma<<<B_TOT/64, 256, 0, stream>>>(hT, hM,
                                           TW1, Tb1, TW2, Tb2, TW3, Tb3,
                                           MW1, Mb1, MW2, Mb2, MW3, Mb3,
                                           FA, TR, out);
}

// Round 9
// 239.460 us; speedup vs baseline: 4.6351x; 1.1817x over previous
//
#include <hip/hip_runtime.h>

#define B_TOT 65536
#define T_LEN 34
#define HD 64
#define LOG2E 1.44269504088896340736f

typedef __attribute__((ext_vector_type(8))) short short8b;
typedef __attribute__((ext_vector_type(4))) short short4b;
typedef __attribute__((ext_vector_type(4))) float f32x4;
typedef __attribute__((ext_vector_type(4))) unsigned int u32x4;

__device__ __forceinline__ float frcp(float x){ return __builtin_amdgcn_rcpf(x); }
__device__ __forceinline__ float fexp2(float x){ return __builtin_amdgcn_exp2f(x); }
__device__ __forceinline__ float fsigmoid(float x){ return frcp(1.0f+__expf(-x)); }
__device__ __forceinline__ float felu(float x){ return x>0.0f ? x : (__expf(x)-1.0f); }

__device__ __forceinline__ unsigned short f2bf_rne(float f){
    unsigned int u = __float_as_uint(f);
    u += 0x7FFFu + ((u >> 16) & 1u);
    return (unsigned short)(u >> 16);
}
__device__ __forceinline__ float bf2f(unsigned short h){
    return __uint_as_float(((unsigned int)h) << 16);
}
__device__ __forceinline__ void split8(const float4& a, const float4& b,
                                       short8b& hi, short8b& lo){
    float f[8] = {a.x,a.y,a.z,a.w,b.x,b.y,b.z,b.w};
    #pragma unroll
    for (int i = 0; i < 8; ++i){
        unsigned short h = f2bf_rne(f[i]);
        hi[i] = (short)h;
        lo[i] = (short)f2bf_rne(f[i] - bf2f(h));
    }
}
__device__ __forceinline__ unsigned int cvt_pk_bf16(float lo, float hi){
    unsigned int r;
    asm("v_cvt_pk_bf16_f32 %0, %1, %2" : "=v"(r) : "v"(lo), "v"(hi));
    return r;
}
__device__ __forceinline__ int hswz(int r){ return ((r ^ (r >> 3)) & 7); }

// ---------------- Kernel A: forward-fill + GRU (MFMA) + attention pooling ----------------
// 512 threads: waves 0-3 = GRU producer (16 rows each), waves 4-7 = pooling
// consumer for the same rows. HL double-buffered per wave-pair; one barrier
// per t-step. Role split keeps hreg (GRU) and num/den (pool) in SEPARATE
// register allocations -> target VGPR <= 128 (occupancy tier).
__global__ __launch_bounds__(512)
void gru_attn_mfma(const float* __restrict__ Xin, const float* __restrict__ FA,
                   const float* __restrict__ Wih, const float* __restrict__ Whh,
                   const float* __restrict__ bih, const float* __restrict__ bhh,
                   const float* __restrict__ swT, const float* __restrict__ swM,
                   float* __restrict__ hT_out, float* __restrict__ hM_out)
{
    __shared__ __align__(16) unsigned short WF[28*512];      // 28 KB: 24 gate + 4 score tiles
    __shared__ __align__(16) unsigned short HL[4][2][1024];  // 16 KB: per-pair h, double-buffered
    __shared__ unsigned int XF[T_LEN*64];                    // 8.5 KB: [t][brow] packed (x,fv)
    __shared__ __align__(8)  unsigned short XWc[12][16][4];  // 1.5 KB: compact ext rows k=0..2

    const int tid  = threadIdx.x;
    const int lane = tid & 63;
    const int wv   = tid >> 6;        // 0..7
    const int l16  = lane & 15;
    const int lhi  = lane >> 4;
    const int wgru = wv & 3;          // row-group owner (shared by producer+consumer)
    const bool isPool = (wv >= 4);

    // ---- stage gate + score B-fragments (k-permuted) ----
    for (int f = wv; f < 28; f += 8) {
        unsigned short* dst = &WF[f*512 + lane*8];
        if (f < 24) {
            int ks = f / 12, nt = f % 12;
            int u_out = nt*16 + l16;
            float scale = (nt < 8) ? -LOG2E : 2.0f*LOG2E;
            #pragma unroll
            for (int j = 0; j < 8; ++j) {
                int k = ks*32 + lhi*8 + j;
                int u_in = (k & 3)*16 + (k >> 2);          // k-perm
                dst[j] = f2bf_rne(scale*Whh[u_out*64 + u_in]);
            }
        } else {
            int s = f - 24;                                 // 0,1: swT halves; 2,3: swM
            const float* src = (s >= 2) ? swM : swT;
            int ks = s & 1;
            #pragma unroll
            for (int j = 0; j < 8; ++j) {
                int k = ks*32 + lhi*8 + j;
                int u_in = (k & 3)*16 + (k >> 2);
                dst[j] = f2bf_rne(LOG2E*src[u_in]);         // replicated across all 16 cols
            }
        }
    }
    // ---- compact ext tiles: [nt][u16] -> (s*Wih0, s*Wih1, bias, 0) ----
    if (tid < 192) {
        int nt  = tid >> 4;
        int u16 = tid & 15;
        int u_abs = (nt < 8) ? (nt*16 + u16) : (128 + (nt-8)*16 + u16);
        float s = (nt < 8) ? -LOG2E : 2.0f*LOG2E;
        float bias = (nt < 8) ? -LOG2E*(bih[u_abs] + bhh[u_abs])
                              : 2.0f*LOG2E*bih[u_abs];
        XWc[nt][u16][0] = f2bf_rne(s*Wih[u_abs*2]);
        XWc[nt][u16][1] = f2bf_rne(s*Wih[u_abs*2+1]);
        XWc[nt][u16][2] = f2bf_rne(bias);
        XWc[nt][u16][3] = 0;
    }
    // ---- zero both h buffers ----
    for (int i = tid; i < 4*2*1024; i += 512)
        (&HL[0][0][0])[i] = 0;

    // ---- forward fill (segmented LOCF); lane = time; 8 rows per wave ----
    for (int i = 0; i < 8; ++i) {
        int brow = wv*8 + i;
        int row  = blockIdx.x*64 + brow;
        float X = 0.0f, fa = 0.0f; int idx = -1;
        if (lane < T_LEN) {
            X  = Xin[row*T_LEN + lane];
            fa = FA [row*T_LEN + lane];
            if (X != 0.0f) idx = lane;
        }
        #pragma unroll
        for (int off = 1; off < 64; off <<= 1) {
            int v = __shfl_up(idx, off);
            if (lane >= off && v > idx) idx = v;
        }
        int gsrc = idx < 0 ? 0 : idx;
        float Xg = __shfl(X,  gsrc);
        float fg = __shfl(fa, gsrc);
        if (idx < 0) { Xg = 0.0f; fg = 0.0f; }
        if (lane < T_LEN)
            XF[lane*64 + brow] =
                (unsigned int)f2bf_rne(Xg) | ((unsigned int)f2bf_rne(fg) << 16);
    }

    __syncthreads();

    // common per-lane addresses
    const int sA    = hswz(l16) << 3;                       // in shorts
    const int aoff0 = l16*64 + (( lhi   *8) ^ sA);
    const int aoff1 = l16*64 + (((4+lhi)*8) ^ sA);
    const f32x4 zero4 = (f32x4){0.f, 0.f, 0.f, 0.f};
    const unsigned short* WFl = &WF[lane*8];

    if (!isPool) {
        // ================= GRU producer =================
        __builtin_amdgcn_s_setprio(1);
        const unsigned int extk2 = (lhi == 0) ? 0x00003f80u : 0u;  // bf16(1.0) in k=2
        const bool ext0 = (lhi == 0);
        const uint2* XWp = reinterpret_cast<const uint2*>(&XWc[0][0][0]);
        float biasN[4];
        #pragma unroll
        for (int g = 0; g < 4; ++g) biasN[g] = 2.0f*LOG2E*bhh[128 + g*16 + l16];

        float2 hreg2[4][2];
        #pragma unroll
        for (int q = 0; q < 4; ++q) { hreg2[q][0] = make_float2(0.f,0.f);
                                      hreg2[q][1] = make_float2(0.f,0.f); }

        for (int t = 0; t < T_LEN; ++t) {
            __syncthreads();
            const unsigned short* pb = &HL[wgru][(t+1)&1][0];
            unsigned short*       cb = &HL[wgru][ t   &1][0];
            short8b a0 = *reinterpret_cast<const short8b*>(&pb[aoff0]);
            short8b a1 = *reinterpret_cast<const short8b*>(&pb[aoff1]);
            unsigned int xw = XF[t*64 + wgru*16 + l16];
            u32x4 aeu = { ext0 ? xw : 0u, extk2, 0u, 0u };
            short8b aext = __builtin_bit_cast(short8b, aeu);

            #pragma unroll
            for (int g = 0; g < 4; ++g) {
                uint2 er = XWp[(g   )*16 + l16];
                uint2 ez = XWp[(4+g )*16 + l16];
                uint2 en = XWp[(8+g )*16 + l16];
                u32x4 bru = { ext0 ? er.x : 0u, ext0 ? er.y : 0u, 0u, 0u };
                u32x4 bzu = { ext0 ? ez.x : 0u, ext0 ? ez.y : 0u, 0u, 0u };
                u32x4 bnu = { ext0 ? en.x : 0u, ext0 ? en.y : 0u, 0u, 0u };

                f32x4 ar = __builtin_amdgcn_mfma_f32_16x16x32_bf16(
                    aext, __builtin_bit_cast(short8b, bru), zero4, 0,0,0);
                ar = __builtin_amdgcn_mfma_f32_16x16x32_bf16(
                    a0, *reinterpret_cast<const short8b*>(WFl + (g   )*512), ar, 0,0,0);
                ar = __builtin_amdgcn_mfma_f32_16x16x32_bf16(
                    a1, *reinterpret_cast<const short8b*>(WFl + (12+g)*512), ar, 0,0,0);
                f32x4 az = __builtin_amdgcn_mfma_f32_16x16x32_bf16(
                    aext, __builtin_bit_cast(short8b, bzu), zero4, 0,0,0);
                az = __builtin_amdgcn_mfma_f32_16x16x32_bf16(
                    a0, *reinterpret_cast<const short8b*>(WFl + (4+g )*512), az, 0,0,0);
                az = __builtin_amdgcn_mfma_f32_16x16x32_bf16(
                    a1, *reinterpret_cast<const short8b*>(WFl + (16+g)*512), az, 0,0,0);
                f32x4 anx = __builtin_amdgcn_mfma_f32_16x16x32_bf16(
                    aext, __builtin_bit_cast(short8b, bnu), zero4, 0,0,0);
                f32x4 anh = __builtin_amdgcn_mfma_f32_16x16x32_bf16(
                    a0, *reinterpret_cast<const short8b*>(WFl + (8+g )*512), zero4, 0,0,0);
                anh = __builtin_amdgcn_mfma_f32_16x16x32_bf16(
                    a1, *reinterpret_cast<const short8b*>(WFl + (20+g)*512), anh, 0,0,0);
                #pragma unroll
                for (int q = 0; q < 4; ++q) {
                    float r  = frcp(1.0f + fexp2(ar[q]));
                    float z  = frcp(1.0f + fexp2(az[q]));
                    float v  = fmaf(r, anh[q], fmaf(r, biasN[g], anx[q]));
                    float n  = fmaf(-2.0f, frcp(1.0f + fexp2(v)), 1.0f);
                    float h  = (g & 1) ? hreg2[q][g>>1].y : hreg2[q][g>>1].x;
                    float hn = fmaf(z, h - n, n);
                    if (g & 1) hreg2[q][g>>1].y = hn; else hreg2[q][g>>1].x = hn;
                }
            }
            // packed h writeback: one b64 per q (k-permuted layout)
            #pragma unroll
            for (int q = 0; q < 4; ++q) {
                int rloc = lhi*4 + q;
                unsigned int d0 = cvt_pk_bf16(hreg2[q][0].x, hreg2[q][0].y);
                unsigned int d1 = cvt_pk_bf16(hreg2[q][1].x, hreg2[q][1].y);
                int so = rloc*64 + ((l16*4) ^ (hswz(rloc) << 3));
                *reinterpret_cast<uint2*>(&cb[so]) = make_uint2(d0, d1);
            }
        }
        __syncthreads();   // match pool branch's final barrier
    } else {
        // ================= pooling consumer =================
        float2 numT2[4][2], numM2[4][2];
        float  denT[4] = {}, denM[4] = {};
        #pragma unroll
        for (int q = 0; q < 4; ++q)
            #pragma unroll
            for (int j = 0; j < 2; ++j) {
                numT2[q][j] = make_float2(0.f, 0.f);
                numM2[q][j] = make_float2(0.f, 0.f);
            }

        for (int t = 0; t < T_LEN; ++t) {
            __syncthreads();
            if (t == 0) continue;     // h_{-1} not pooled
            const unsigned short* pb = &HL[wgru][(t+1)&1][0];   // h_{t-1}
            short8b a0 = *reinterpret_cast<const short8b*>(&pb[aoff0]);
            short8b a1 = *reinterpret_cast<const short8b*>(&pb[aoff1]);
            f32x4 accT = __builtin_amdgcn_mfma_f32_16x16x32_bf16(
                a0, *reinterpret_cast<const short8b*>(WFl + 24*512), zero4, 0,0,0);
            accT = __builtin_amdgcn_mfma_f32_16x16x32_bf16(
                a1, *reinterpret_cast<const short8b*>(WFl + 25*512), accT, 0,0,0);
            f32x4 accM = __builtin_amdgcn_mfma_f32_16x16x32_bf16(
                a0, *reinterpret_cast<const short8b*>(WFl + 26*512), zero4, 0,0,0);
            accM = __builtin_amdgcn_mfma_f32_16x16x32_bf16(
                a1, *reinterpret_cast<const short8b*>(WFl + 27*512), accM, 0,0,0);
            #pragma unroll
            for (int q = 0; q < 4; ++q) {
                int rloc = lhi*4 + q;
                uint2 hq = *reinterpret_cast<const uint2*>(
                    &pb[rloc*64 + ((l16*4) ^ (hswz(rloc) << 3))]);
                float g0 = __uint_as_float(hq.x << 16);
                float g1 = __uint_as_float(hq.x & 0xFFFF0000u);
                float g2 = __uint_as_float(hq.y << 16);
                float g3 = __uint_as_float(hq.y & 0xFFFF0000u);
                float eT = fexp2(accT[q]);
                float eM = fexp2(accM[q]);
                denT[q] += eT; denM[q] += eM;
                numT2[q][0].x = fmaf(eT, g0, numT2[q][0].x);
                numT2[q][0].y = fmaf(eT, g1, numT2[q][0].y);
                numT2[q][1].x = fmaf(eT, g2, numT2[q][1].x);
                numT2[q][1].y = fmaf(eT, g3, numT2[q][1].y);
                numM2[q][0].x = fmaf(eM, g0, numM2[q][0].x);
                numM2[q][0].y = fmaf(eM, g1, numM2[q][0].y);
                numM2[q][1].x = fmaf(eM, g2, numM2[q][1].x);
                numM2[q][1].y = fmaf(eM, g3, numM2[q][1].y);
            }
        }
        __syncthreads();   // h_33 (buf[1]) complete
        {
            const unsigned short* pb = &HL[wgru][1][0];          // h_33 (33&1 = 1)
            short8b a0 = *reinterpret_cast<const short8b*>(&pb[aoff0]);
            short8b a1 = *reinterpret_cast<const short8b*>(&pb[aoff1]);
            f32x4 accT = __builtin_amdgcn_mfma_f32_16x16x32_bf16(
                a0, *reinterpret_cast<const short8b*>(WFl + 24*512), zero4, 0,0,0);
            accT = __builtin_amdgcn_mfma_f32_16x16x32_bf16(
                a1, *reinterpret_cast<const short8b*>(WFl + 25*512), accT, 0,0,0);
            f32x4 accM = __builtin_amdgcn_mfma_f32_16x16x32_bf16(
                a0, *reinterpret_cast<const short8b*>(WFl + 26*512), zero4, 0,0,0);
            accM = __builtin_amdgcn_mfma_f32_16x16x32_bf16(
                a1, *reinterpret_cast<const short8b*>(WFl + 27*512), accM, 0,0,0);
            #pragma unroll
            for (int q = 0; q < 4; ++q) {
                int rloc = lhi*4 + q;
                uint2 hq = *reinterpret_cast<const uint2*>(
                    &pb[rloc*64 + ((l16*4) ^ (hswz(rloc) << 3))]);
                float g0 = __uint_as_float(hq.x << 16);
                float g1 = __uint_as_float(hq.x & 0xFFFF0000u);
                float g2 = __uint_as_float(hq.y << 16);
                float g3 = __uint_as_float(hq.y & 0xFFFF0000u);
                float eT = fexp2(accT[q]);
                float eM = fexp2(accM[q]);
                denT[q] += eT; denM[q] += eM;
                numT2[q][0].x = fmaf(eT, g0, numT2[q][0].x);
                numT2[q][0].y = fmaf(eT, g1, numT2[q][0].y);
                numT2[q][1].x = fmaf(eT, g2, numT2[q][1].x);
                numT2[q][1].y = fmaf(eT, g3, numT2[q][1].y);
                numM2[q][0].x = fmaf(eM, g0, numM2[q][0].x);
                numM2[q][0].y = fmaf(eM, g1, numM2[q][0].y);
                numM2[q][1].x = fmaf(eM, g2, numM2[q][1].x);
                numM2[q][1].y = fmaf(eM, g3, numM2[q][1].y);
            }
        }
        const int rowbase = blockIdx.x*64 + wgru*16;
        #pragma unroll
        for (int q = 0; q < 4; ++q) {
            int row = rowbase + lhi*4 + q;
            float rT = frcp(denT[q]), rM = frcp(denM[q]);
            #pragma unroll
            for (int j = 0; j < 2; ++j) {
                hT_out[row*HD + (2*j  )*16 + l16] = numT2[q][j].x*rT;
                hT_out[row*HD + (2*j+1)*16 + l16] = numT2[q][j].y*rT;
                hM_out[row*HD + (2*j  )*16 + l16] = numM2[q][j].x*rM;
                hM_out[row*HD + (2*j+1)*16 + l16] = numM2[q][j].y*rM;
            }
        }
    }
}

// ---------------- Kernel B: MFMA MLP heads + T10/M0 + X_out (unchanged) ----------------
__global__ __launch_bounds__(256)
void mlp_mfma(const float* __restrict__ hT, const float* __restrict__ hM,
    const float* __restrict__ TW1, const float* __restrict__ Tb1,
    const float* __restrict__ TW2, const float* __restrict__ Tb2,
    const float* __restrict__ TW3, const float* __restrict__ Tb3,
    const float* __restrict__ MW1, const float* __restrict__ Mb1,
    const float* __restrict__ MW2, const float* __restrict__ Mb2,
    const float* __restrict__ MW3, const float* __restrict__ Mb3,
    const float* __restrict__ FA, const float* __restrict__ TR,
    float* __restrict__ out)
{
    __shared__ __align__(16) unsigned short xh[2*64*64];
    __shared__ __align__(16) unsigned short h1s[64*256];
    __shared__ float praw[4][64];
    __shared__ float rawv[2][64];
    __shared__ float Es[64], M0s[64];

    const int tid  = threadIdx.x;
    const int lane = tid & 63;
    const int wv   = tid >> 6;
    const int l16  = lane & 15;
    const int lhi  = lane >> 4;
    const int row0 = blockIdx.x*64;

    {
        int r  = tid >> 2;
        int k0 = (tid & 3) * 16;
        int rx = r & 7;
        const float* pT = &hT[(row0+r)*64 + k0];
        const float* pM = &hM[(row0+r)*64 + k0];
        #pragma unroll
        for (int j = 0; j < 4; ++j) {
            float4 vT = *reinterpret_cast<const float4*>(pT + 4*j);
            float4 vM = *reinterpret_cast<const float4*>(pM + 4*j);
            int kk = k0 + 4*j;
            int ad = r*64 + ((((kk>>3) ^ rx))<<3) + (kk&7);
            short4b sT = { (short)f2bf_rne(vT.x), (short)f2bf_rne(vT.y),
                           (short)f2bf_rne(vT.z), (short)f2bf_rne(vT.w) };
            short4b sM = { (short)f2bf_rne(vM.x), (short)f2bf_rne(vM.y),
                           (short)f2bf_rne(vM.z), (short)f2bf_rne(vM.w) };
            *reinterpret_cast<short4b*>(&xh[ad])        = sT;
            *reinterpret_cast<short4b*>(&xh[4096 + ad]) = sM;
        }
        for (int i = tid; i < 64*24; i += 256) {
            int rr = i / 24, kk = 200 + i % 24;
            h1s[rr*256 + ((((kk>>3) ^ (rr&7)))<<3) + (kk&7)] = 0;
        }
    }
    __syncthreads();

    for (int brn = 0; brn < 2; ++brn) {
        const float* W1 = brn ? MW1 : TW1; const float* b1 = brn ? Mb1 : Tb1;
        const float* W2 = brn ? MW2 : TW2; const float* b2 = brn ? Mb2 : Tb2;
        const float* W3 = brn ? MW3 : TW3; const float* b3 = brn ? Mb3 : Tb3;

        for (int s = 0; s < 4; ++s) {
            int nt = wv + 4*s;
            if (nt > 12) break;
            int n  = nt*16 + l16;
            int nc = n < 200 ? n : 199;
            float bv = b1[nc];
            f32x4 acc[4];
            #pragma unroll
            for (int mt = 0; mt < 4; ++mt) acc[mt] = (f32x4){bv,bv,bv,bv};
            #pragma unroll
            for (int ks = 0; ks < 2; ++ks) {
                int k0 = ks*32 + lhi*8;
                const float* wp = &W1[nc*64 + k0];
                float4 w0 = *reinterpret_cast<const float4*>(wp);
                float4 w1 = *reinterpret_cast<const float4*>(wp + 4);
                short8b bh, bl;
                split8(w0, w1, bh, bl);
                #pragma unroll
                for (int mt = 0; mt < 4; ++mt) {
                    int rr = mt*16 + l16;
                    short8b a = *reinterpret_cast<const short8b*>(
                        &xh[brn*4096 + rr*64 + ((((k0>>3) ^ (rr&7)))<<3)]);
                    acc[mt] = __builtin_amdgcn_mfma_f32_16x16x32_bf16(a, bh, acc[mt], 0,0,0);
                    acc[mt] = __builtin_amdgcn_mfma_f32_16x16x32_bf16(a, bl, acc[mt], 0,0,0);
                }
            }
            if (n < 200) {
                #pragma unroll
                for (int mt = 0; mt < 4; ++mt) {
                    #pragma unroll
                    for (int q = 0; q < 4; ++q) {
                        int rr = mt*16 + lhi*4 + q;
                        h1s[rr*256 + ((((n>>3) ^ (rr&7)))<<3) + (n&7)] =
                            f2bf_rne(felu(acc[mt][q]));
                    }
                }
            }
        }
        __syncthreads();

        float p[4][4] = {};
        for (int s = 0; s < 4; ++s) {
            int nt = wv + 4*s;
            if (nt > 12) break;
            int n  = nt*16 + l16;
            int nc = n < 200 ? n : 199;
            float w3v = (n < 200) ? W3[nc] : 0.0f;
            float bv = b2[nc];
            f32x4 acc[4];
            #pragma unroll
            for (int mt = 0; mt < 4; ++mt) acc[mt] = (f32x4){bv,bv,bv,bv};
            for (int ks = 0; ks < 7; ++ks) {
                int k0 = ks*32 + lhi*8;
                short8b bh, bl;
                if (k0 + 8 <= 200) {
                    const float* wp = &W2[nc*200 + k0];
                    float4 w0 = *reinterpret_cast<const float4*>(wp);
                    float4 w1 = *reinterpret_cast<const float4*>(wp + 4);
                    split8(w0, w1, bh, bl);
                } else {
                    #pragma unroll
                    for (int i = 0; i < 8; ++i) { bh[i] = 0; bl[i] = 0; }
                }
                #pragma unroll
                for (int mt = 0; mt < 4; ++mt) {
                    int rr = mt*16 + l16;
                    short8b a = *reinterpret_cast<const short8b*>(
                        &h1s[rr*256 + ((((k0>>3) ^ (rr&7)))<<3)]);
                    acc[mt] = __builtin_amdgcn_mfma_f32_16x16x32_bf16(a, bh, acc[mt], 0,0,0);
                    acc[mt] = __builtin_amdgcn_mfma_f32_16x16x32_bf16(a, bl, acc[mt], 0,0,0);
                }
            }
            #pragma unroll
            for (int mt = 0; mt < 4; ++mt)
                #pragma unroll
                for (int q = 0; q < 4; ++q)
                    p[mt][q] = fmaf(w3v, felu(acc[mt][q]), p[mt][q]);
        }
        #pragma unroll
        for (int off = 1; off < 16; off <<= 1) {
            #pragma unroll
            for (int mt = 0; mt < 4; ++mt)
                #pragma unroll
                for (int q = 0; q < 4; ++q)
                    p[mt][q] += __shfl_xor(p[mt][q], off);
        }
        if (l16 == 0) {
            #pragma unroll
            for (int mt = 0; mt < 4; ++mt)
                #pragma unroll
                for (int q = 0; q < 4; ++q)
                    praw[wv][mt*16 + lhi*4 + q] = p[mt][q];
        }
        __syncthreads();
        if (tid < 64)
            rawv[brn][tid] = b3[0] + praw[0][tid] + praw[1][tid] + praw[2][tid] + praw[3][tid];
        __syncthreads();
    }

    if (tid < 64) {
        int row = row0 + tid;
        float T10 = 0.1f + 4.9f*fsigmoid(rawv[0][tid]);
        float M0  = 10000.0f*fsigmoid(rawv[1][tid]);
        Es[tid]  = __expf(-TR[row]/T10);
        M0s[tid] = M0;
        out[(size_t)B_TOT*T_LEN + row]         = T10;
        out[(size_t)B_TOT*T_LEN + B_TOT + row] = M0;
    }
    __syncthreads();
    for (int i = tid; i < 64*T_LEN; i += 256) {
        int rr = i / T_LEN, t = i - rr*T_LEN;
        int row = row0 + rr;
        float fa = FA[row*T_LEN + t];
        float s = __sinf(fa), c = __cosf(fa);
        float Ev = Es[rr];
        out[row*T_LEN + t] = (1.0f - Ev)*s*frcp(1.0f - c*Ev)*M0s[rr];
    }
}

extern "C" void kernel_launch(void* const* d_in, const int* in_sizes, int n_in,
                              void* d_out, int out_size, void* d_ws, size_t ws_size,
                              hipStream_t stream) {
    const float* Xin = (const float*)d_in[0];
    const float* FA  = (const float*)d_in[1];
    const float* TR  = (const float*)d_in[4];
    const float* Wih = (const float*)d_in[5];
    const float* Whh = (const float*)d_in[6];
    const float* bih = (const float*)d_in[7];
    const float* bhh = (const float*)d_in[8];
    const float* swT = (const float*)d_in[9];
    const float* swM = (const float*)d_in[10];
    const float* TW1 = (const float*)d_in[11]; const float* Tb1 = (const float*)d_in[12];
    const float* TW2 = (const float*)d_in[13]; const float* Tb2 = (const float*)d_in[14];
    const float* TW3 = (const float*)d_in[15]; const float* Tb3 = (const float*)d_in[16];
    const float* MW1 = (const float*)d_in[17]; const float* Mb1 = (const float*)d_in[18];
    const float* MW2 = (const float*)d_in[19]; const float* Mb2 = (const float*)d_in[20];
    const float* MW3 = (const float*)d_in[21]; const float* Mb3 = (const float*)d_in[22];
    float* out = (float*)d_out;

    float* hT = (float*)d_ws;
    float* hM = hT + (size_t)B_TOT*HD;

    gru_attn_mfma<<<B_TOT/64, 512, 0, stream>>>(Xin, FA, Wih, Whh, bih, bhh,
                                                swT, swM, hT, hM);
    mlp_mfma<<<B_TOT/64, 256, 0, stream>>>(hT, hM,
                                           TW1, Tb1, TW2, Tb2, TW3, Tb3,
                                           MW1, Mb1, MW2, Mb2, MW3, Mb3,
                                           FA, TR, out);
}